// Round 9
// baseline (19336.107 us; speedup 1.0000x reference)
//
#include <hip/hip_runtime.h>
#include <hip/hip_bf16.h>

typedef __hip_bfloat16 bf16;
typedef _Float16 f16;
typedef _Float16 f16x8 __attribute__((ext_vector_type(8)));
typedef float f32x4 __attribute__((ext_vector_type(4)));
typedef unsigned long long u64;
typedef unsigned short ushort_t;

__device__ __forceinline__ float b2f(bf16 x){ return __bfloat162float(x); }
__device__ __forceinline__ float sigf(float x){ return 1.f/(1.f+expf(-x)); }
__device__ __forceinline__ float splus(float x){ return fmaxf(x,0.f)+log1pf(expf(-fabsf(x))); }
__device__ __forceinline__ float ldf(const void* p, int i, int isf32){
  return isf32 ? ((const float*)p)[i] : __bfloat162float(((const bf16*)p)[i]);
}
// agent-scope coherent ops (bypass per-XCD L2). Proven cross-XCD coherent, no fences.
__device__ __forceinline__ void ast64(u64* p, u64 v){ __hip_atomic_store(p, v, __ATOMIC_RELAXED, __HIP_MEMORY_SCOPE_AGENT); }
__device__ __forceinline__ u64 ald64(u64* p){ return __hip_atomic_load(p, __ATOMIC_RELAXED, __HIP_MEMORY_SCOPE_AGENT); }
__device__ __forceinline__ void ast32(unsigned* p, unsigned v){ __hip_atomic_store(p, v, __ATOMIC_RELAXED, __HIP_MEMORY_SCOPE_AGENT); }
__device__ __forceinline__ unsigned ald32(unsigned* p){ return __hip_atomic_load(p, __ATOMIC_RELAXED, __HIP_MEMORY_SCOPE_AGENT); }

union U4H8 { uint4 u; f16x8 h; };
union U64H4 { u64 u; f16 h[4]; };
union H16 { f16 h; ushort_t s; };

// ---------------- dtype detect ----------------
__global__ void k_detect(const void* __restrict__ emb, int* __restrict__ flag){
  __shared__ float mx[256];
  int tid=threadIdx.x;
  float v = fabsf(__bfloat162float(((const bf16*)emb)[tid]));
  mx[tid]=v; __syncthreads();
  for(int s=128;s>0;s>>=1){ if(tid<s) mx[tid]=fmaxf(mx[tid],mx[tid+s]); __syncthreads(); }
  if(tid==0){ flag[0] = (mx[0]>1000.f) ? 1 : 0; flag[1] = 0; }
}

// ---------------- setup ----------------
// embW[row][v] = b0[row] + sum_k emb[v][k]*Wi0[row][k]   (row-major [2048][256])
__global__ void k_embW(const void* __restrict__ emb, const void* __restrict__ Wi0,
                       const void* __restrict__ b0,
                       const int* __restrict__ flags, float* __restrict__ embW){
  int f=flags[0];
  int row = blockIdx.x;
  __shared__ float w[512];
  for(int k=threadIdx.x;k<512;k+=256) w[k]=ldf(Wi0,row*576+k,f);
  __syncthreads();
  int v = threadIdx.x;
  float acc=ldf(b0,row,f);
  #pragma unroll 4
  for(int k=0;k<512;k++) acc += ldf(emb,v*512+k,f)*w[k];
  embW[row*256+v]=acc;
}

// ---- layer-0 sliced prepack, TRANSPOSED rows (row-in-tile = dd*4+G) so one
// f32x4 acc holds all 4 gates of one dim (register-local nonlinearity).
__global__ void k_wpkA(const void* __restrict__ Wh0, const void* __restrict__ Wi0,
                       const int* __restrict__ flags, ushort_t* __restrict__ PA){
  int f=flags[0];
  int idx=blockIdx.x*256+threadIdx.x;
  if(idx>=1179648) return;
  int j=idx&7, l=(idx>>3)&63, rest=idx>>9;
  int c=rest%18, t2=rest/18, w=t2&7, r=t2>>3;
  int tr=l&15, q4=l>>4;
  int G=tr&3, dd=tr>>2;
  int row=G*512 + r*32 + w*4 + dd;
  int k=c*32 + q4*8 + j;
  float val = (k<512)? ldf(Wh0,row*512+k,f) : ldf(Wi0,row*576+k,f);
  H16 hx; hx.h=(f16)val; PA[idx]=hx.s;
}
// ---- layer-1 sliced prepack, transposed ----
__global__ void k_wpkB(const void* __restrict__ Wi1, const void* __restrict__ Wh1,
                       const int* __restrict__ flags, ushort_t* __restrict__ PB){
  int f=flags[0];
  int idx=blockIdx.x*256+threadIdx.x;
  if(idx>=2097152) return;
  int j=idx&7, l=(idx>>3)&63, rest=idx>>9;
  int c=rest&31, t2=rest>>5, w=t2&7, r=t2>>3;
  int tr=l&15, q4=l>>4;
  int G=tr&3, dd=tr>>2;
  int row=G*512 + r*32 + w*4 + dd;
  int k=c*32 + q4*8 + j;
  float val = (k<512)? ldf(Wi1,row*512+k,f) : ldf(Wh1,row*512+k-512,f);
  H16 hx; hx.h=(f16)val; PB[idx]=hx.s;
}

// W_if prepack into MFMA A-frags; zeroes FL; loads b_ifF.
__global__ void k_wifP(const void* __restrict__ W_if, const void* __restrict__ b_if,
                       const int* __restrict__ flags,
                       ushort_t* __restrict__ PW, float* __restrict__ b_ifF,
                       unsigned* __restrict__ FLz){
  int f=flags[0];
  int idx=blockIdx.x*256+threadIdx.x;
  if(idx<73728){
    int j=idx&7, l=(idx>>3)&63, c=(idx>>9)&15, tile=idx>>13;
    int row=tile*16+(l&15);
    int k=c*32+(l>>4)*8+j;
    float val=(row<135)? ldf(W_if,row*512+k,f) : 0.f;
    H16 hx; hx.h=(f16)val; PW[idx]=hx.s;
  }
  if(idx<64) FLz[idx]=0u;
  if(idx<135) b_ifF[idx]=ldf(b_if,idx,f);
}

__global__ void k_wc(const void* __restrict__ W_fc, const void* __restrict__ W_out,
                     const void* __restrict__ b_out, const void* __restrict__ b_fc,
                     const int* __restrict__ flags,
                     float* __restrict__ Wc, float* __restrict__ bc){
  int f=flags[0];
  int idx=blockIdx.x*256+threadIdx.x;
  int v=idx/576, j=idx-v*576;
  float acc=0.f;
  #pragma unroll 4
  for(int d=0;d<512;d++) acc += ldf(W_fc,v*512+d,f)*ldf(W_out,d*576+j,f);
  Wc[idx]=acc;
  if(j==0){
    float a=ldf(b_fc,v,f);
    for(int d=0;d<512;d++) a += ldf(W_fc,v*512+d,f)*ldf(b_out,d,f);
    bc[v]=a;
  }
}

// ---------------- grouped recurrence (2-hop) + full weight prefetch pipeline ----------------
// 4 groups x 16 blocks; block (g,r) owns dims [32r,32r+32); L2-resident slices.
// NEW vs round 8: EVERY MFMA section's weight frags are register-prefetched so
// L2 latency lands inside hops/other work (pattern proven by pfB in round 7):
//   pfA1 (A1 Wh0 chunks): issued at end of B p2 of the previous iteration.
//   pfP3/pfP3x (xi W_if): issued before the beta wait.
//   pfB1 (cover2 Wh1 chunks): issued before the machinery (no VMEM there).
//   pfB2 (B p2 Wi1 chunks): issued in cover2 before the alpha wait (existing).
// waves_per_eu(2,2) gives a 256-VGPR budget at unchanged 2 waves/SIMD.
__attribute__((amdgpu_waves_per_eu(2,2)))
__global__ void __launch_bounds__(512) k_dnc3(
    const int* __restrict__ tokens, const void* __restrict__ b1, const int* __restrict__ flags,
    const float* __restrict__ embW, const ushort_t* __restrict__ PA, const ushort_t* __restrict__ PB,
    const ushort_t* __restrict__ PW, const float* __restrict__ b_ifF,
    u64* GX0, u64* GX1, unsigned* FL,
    bf16* __restrict__ cat)
{
  const int bid = blockIdx.x;
  const int g   = bid>>4, r = bid&15;
  const int tid = threadIdx.x;
  const int wv  = tid>>6, l = tid&63;
  const int lm  = l&15,  q4 = l>>4;
  const int mb  = tid>>5, mu = tid&31;     // machinery mapping (batch, slot)
  const int f32i = flags[0];

  __shared__ __align__(16) u64 HB[4352];   // [0..2047] h0 | [2048..4095] h1 | [4096..4351] lr frags
  __shared__ f16  sh_pub[512];
  __shared__ int  tokL[16];
  __shared__ float b_ifL[144];
  __shared__ float xis2[16*149];
  __shared__ float s_pre[16*112];          // precomputed transcendentals per batch
  __shared__ float s_mem[1280], s_mem2[1280], s_link[400], s_link2[400];
  __shared__ float s_prec[80], s_prec2[80], s_rwp[320], s_rw[320];
  __shared__ float s_wwp[80], s_ww[80], s_usage[80], s_wl[80];
  __shared__ float s_rl[320], s_fwd[320], s_bwd[320], s_wsum[16];
  __shared__ float rvbuf[1024];

#define WAITG(TGT) do{ if(tid<16){ unsigned _tg=(unsigned)(TGT); int _wd=0; \
    while(ald32(&FL[g*16+tid]) < _tg && _wd<50000000){ __builtin_amdgcn_s_sleep(1); _wd++; } } \
  __syncthreads(); }while(0)
#define PUBF(VAL) do{ __syncthreads(); \
  if(tid==0) ast32(&FL[g*16+r],(unsigned)(VAL)); }while(0)
#define XI(i) xis2[mb*149+(i)]
#define WB() __builtin_amdgcn_wave_barrier()

  const f16x8* HBv=(const f16x8*)HB;
  const uint4* PAv=(const uint4*)PA;
  const uint4* PBv=(const uint4*)PB;
  const uint4* PWv=(const uint4*)PW;

  // per-thread biases for (dim1 = r*32+wv*4+q4), 4 gates
  const int dim1 = r*32 + wv*4 + q4;
  const float b1Li=ldf(b1,dim1,f32i), b1Lf=ldf(b1,512+dim1,f32i),
              b1Lg=ldf(b1,1024+dim1,f32i), b1Lo=ldf(b1,1536+dim1,f32i);

  if(tid<144) b_ifL[tid]=(tid<135)? b_ifF[tid] : 0.f;
  for(int i=tid;i<1280;i+=512) s_mem[i]=0.f;
  for(int i=tid;i<400;i+=512) s_link[i]=0.f;
  for(int i=tid;i<320;i+=512) s_rwp[i]=0.f;
  if(tid<80){ s_prec[tid]=0.f; s_wwp[tid]=0.f; s_usage[tid]=0.f; }
  float c0s=0.f, c1s=0.f;
  uint4 pfA1[16];

  // ---- prologue t=0: h0(0)=f(em(0)); h1(0)=g(h0(0)) ----
  if(tid<16) tokL[tid]=tokens[(g*16+tid)*512];
  __syncthreads();
  {
    int tok=tokL[lm];
    float ei=embW[dim1*256+tok];
    float eg=embW[262144+dim1*256+tok];
    float eo=embW[393216+dim1*256+tok];
    c0s = sigf(ei)*tanhf(eg);
    sh_pub[(wv*4+q4)*16+lm]=(f16)(sigf(eo)*tanhf(c0s));
  }
  __syncthreads();
  if(tid<128){
    int ks=tid>>4, b2=tid&15;
    U64H4 pk;
    #pragma unroll
    for(int i=0;i<4;i++) pk.h[i]=sh_pub[(ks*4+i)*16+b2];
    ast64(&GX0[g*4096+((4*r+(ks>>1))*16+b2)*2+(ks&1)], pk.u);
  }
  PUBF(2u);            // alpha(0)
  WAITG(2u);
  {
    u64 s0=ald64(&GX0[g*4096+tid      ]);
    u64 s1=ald64(&GX0[g*4096+tid+512  ]);
    u64 s2=ald64(&GX0[g*4096+tid+1024 ]);
    u64 s3=ald64(&GX0[g*4096+tid+1536 ]);
    HB[tid]=s0; HB[tid+512]=s1; HB[tid+1024]=s2; HB[tid+1536]=s3;
  }
  __syncthreads();
  {
    f32x4 acc1=(f32x4){0.f,0.f,0.f,0.f};
    #pragma unroll
    for(int c=0;c<16;c++){
      U4H8 wf; wf.u=PBv[((r*8+wv)*32+c)*64+l];
      f16x8 bfr=HBv[(c*4+q4)*16+lm];
      acc1=__builtin_amdgcn_mfma_f32_16x16x32_f16(wf.h,bfr,acc1,0,0,0);
    }
    float gi=acc1[0]+b1Li, gg=acc1[2]+b1Lg, go=acc1[3]+b1Lo;
    c1s=sigf(gi)*tanhf(gg);
    sh_pub[(wv*4+q4)*16+lm]=(f16)(sigf(go)*tanhf(c1s));
  }
  __syncthreads();
  if(tid<128){
    int ks=tid>>4, b2=tid&15;
    U64H4 pk;
    #pragma unroll
    for(int i=0;i<4;i++) pk.h[i]=sh_pub[(ks*4+i)*16+b2];
    ast64(&GX1[g*4096+((4*r+(ks>>1))*16+b2)*2+(ks&1)], pk.u);
  }
  PUBF(3u);            // beta(0)
  // prefetch A1 weights for tt=0
  #pragma unroll
  for(int c=0;c<16;c++) pfA1[c]=PAv[((r*8+wv)*18+c)*64+l];

  // ---- main loop ----
  for(int tt=0;tt<512;tt++){
    const int p=tt&1, pn=p^1;

    // cover1: A p1 (16 chunks, PREFETCHED weights) on h0(tt) in HB[0..2047]
    f32x4 accA=(f32x4){0.f,0.f,0.f,0.f};
    #pragma unroll
    for(int c=0;c<16;c++){
      U4H8 wf; wf.u=pfA1[c];
      f16x8 bfr=HBv[(c*4+q4)*16+lm];
      accA=__builtin_amdgcn_mfma_f32_16x16x32_f16(wf.h,bfr,accA,0,0,0);
    }
    // prefetch em(tt+1), A2 lr-frag weights, and P3 W_if frags (hop-covered)
    float em0,em1,em2,em3;
    {
      int tn=(tt<511)?tt+1:511;
      int tok=tokens[(g*16+lm)*512+tn];
      em0=embW[dim1*256+tok]; em1=embW[131072+dim1*256+tok];
      em2=embW[262144+dim1*256+tok]; em3=embW[393216+dim1*256+tok];
    }
    uint4 pfA2[2];
    #pragma unroll
    for(int c2=0;c2<2;c2++) pfA2[c2]=PAv[((r*8+wv)*18+16+c2)*64+l];
    uint4 pfP3[16];
    #pragma unroll
    for(int cc=0;cc<16;cc++) pfP3[cc]=PWv[(wv*16+cc)*64+l];
    uint4 pfP3x[16];
    if(wv==0){
      #pragma unroll
      for(int cc=0;cc<16;cc++) pfP3x[cc]=PWv[(128+cc)*64+l];
    }

    WAITG(2*tt+3);     // beta(tt)

    // stage h1(tt) -> HB[2048..4095]
    {
      u64 s0=ald64(&GX1[g*4096+p*2048+tid      ]);
      u64 s1=ald64(&GX1[g*4096+p*2048+tid+512  ]);
      u64 s2=ald64(&GX1[g*4096+p*2048+tid+1024 ]);
      u64 s3=ald64(&GX1[g*4096+p*2048+tid+1536 ]);
      HB[2048+tid]=s0; HB[2048+tid+512]=s1; HB[2048+tid+1024]=s2; HB[2048+tid+1536]=s3;
    }
    __syncthreads();

    // ====== P3(tt): xi = W_if @ h1 via MFMA (prefetched weights) ======
    {
      f32x4 xa=(f32x4){0.f,0.f,0.f,0.f};
      #pragma unroll
      for(int cc=0;cc<16;cc++){
        U4H8 t4; t4.u=pfP3[cc];
        f16x8 bfr=HBv[1024+(cc*4+q4)*16+lm];
        xa=__builtin_amdgcn_mfma_f32_16x16x32_f16(t4.h,bfr,xa,0,0,0);
      }
      #pragma unroll
      for(int reg=0;reg<4;reg++){
        int row=wv*16+q4*4+reg;
        xis2[lm*149+row]=xa[reg]+b_ifL[row];
      }
      if(wv==0){
        f32x4 xb=(f32x4){0.f,0.f,0.f,0.f};
        #pragma unroll
        for(int cc=0;cc<16;cc++){
          U4H8 t4; t4.u=pfP3x[cc];
          f16x8 bfr=HBv[1024+(cc*4+q4)*16+lm];
          xb=__builtin_amdgcn_mfma_f32_16x16x32_f16(t4.h,bfr,xb,0,0,0);
        }
        #pragma unroll
        for(int reg=0;reg<4;reg++){
          int row=128+q4*4+reg;
          xis2[lm*149+row]=xb[reg]+b_ifL[row];
        }
      }
    }
    // prefetch cover2's Wh1 chunks (consumed after machinery; no VMEM in between)
    uint4 pfB1[16];
    #pragma unroll
    for(int c=16;c<32;c++) pfB1[c-16]=PBv[((r*8+wv)*32+c)*64+l];
    __syncthreads();

    // ====== machinery (wave-local per batch, half-wave = 32 lanes) ======
    if(mu<16){
      s_pre[mb*112+mu]    =tanhf(XI(68+mu));
      s_pre[mb*112+16+mu] =sigf (XI(85+mu));
      s_pre[mb*112+32+mu] =tanhf(XI(101+mu));
    }
    s_pre[mb*112+48+mu]   =tanhf(XI(mu));
    s_pre[mb*112+48+32+mu]=tanhf(XI(32+mu));
    WB();
    // M1
    if(mu<5){
      int m=mu;
      float u=s_usage[mb*5+m]+(1.f-s_usage[mb*5+m])*s_wwp[mb*5+m];
      float psi=1.f;
      #pragma unroll
      for(int rr=0;rr<4;rr++) psi *= 1.f - sigf(XI(117+rr))*s_rwp[mb*20+rr*5+m];
      u*=psi; s_usage[mb*5+m]=u;
      float nm=0.f,dt=0.f,nk=0.f;
      #pragma unroll
      for(int w=0;w<16;w++){
        float mv=s_mem[mb*80+m*16+w], kv=s_pre[mb*112+w];
        nm+=mv*mv; dt+=mv*kv; nk+=kv*kv;
      }
      float sim=dt/((sqrtf(nm)+1e-6f)*(sqrtf(nk)+1e-6f));
      s_wl[mb*5+m]=sim*splus(XI(84));
    }
    WB();
    // M2a
    if(mu<5){
      int m=mu;
      float mx=s_wl[mb*5];
      #pragma unroll
      for(int j=1;j<5;j++) mx=fmaxf(mx,s_wl[mb*5+j]);
      float e=expf(s_wl[mb*5+m]-mx);
      float u=1e-6f+(1.f-1e-6f)*s_usage[mb*5+m];
      s_rl [mb*20+m]=u;   // scratch (overwritten by M4)
      s_bwd[mb*20+m]=e;   // scratch (overwritten by M4)
    }
    WB();
    // M2b: stable-rank allocation
    if(mu<5){
      int m=mu;
      float u=s_rl[mb*20+m], e=s_bwd[mb*20+m];
      float s=0.f, prod=1.f;
      #pragma unroll
      for(int j=0;j<5;j++){
        s+=s_bwd[mb*20+j];
        float uj=s_rl[mb*20+j];
        if(uj<u || (uj==u && j<m)) prod*=uj;
      }
      float wcw=e/s;
      float alloc=(1.f-u)*prod;
      float ag=sigf(XI(121)), wgg=sigf(XI(122));
      s_ww[mb*5+m]=wgg*(ag*alloc+(1.f-ag)*wcw);
    }
    WB();
    if(mu==0){
      float ws=0.f;
      #pragma unroll
      for(int m=0;m<5;m++) ws+=s_ww[mb*5+m];
      s_wsum[mb]=ws;
    }
    WB();
    // M3
    for(int k=mu;k<80;k+=32){
      int m=k>>4,w=k&15;
      float er=s_pre[mb*112+16+w], wv2=s_pre[mb*112+32+w];
      float w_=s_ww[mb*5+m];
      s_mem2[mb*80+k]=s_mem[mb*80+k]*(1.f-w_*er)+w_*wv2;
    }
    if(mu<25){
      int i=mu/5, j=mu-5*i;
      s_link2[mb*25+mu]=(i==j)?0.f:((1.f-s_ww[mb*5+i]-s_ww[mb*5+j])*s_link[mb*25+mu]+s_ww[mb*5+i]*s_prec[mb*5+j]);
    } else if(mu<30){
      int j=mu-25;
      s_prec2[mb*5+j]=(1.f-s_wsum[mb])*s_prec[mb*5+j]+s_ww[mb*5+j];
    }
    WB();
    // M4
    if(mu<20){
      int rr=mu/5, m=mu-5*rr;
      float nm=0.f,dt=0.f,nk=0.f;
      #pragma unroll
      for(int w=0;w<16;w++){
        float mv=s_mem2[mb*80+m*16+w], kv=s_pre[mb*112+48+rr*16+w];
        nm+=mv*mv; dt+=mv*kv; nk+=kv*kv;
      }
      float sim=dt/((sqrtf(nm)+1e-6f)*(sqrtf(nk)+1e-6f));
      s_rl[mb*20+mu]=sim*splus(XI(64+rr));
      float af=0.f, ab=0.f;
      #pragma unroll
      for(int j=0;j<5;j++) af+=s_link2[mb*25+m*5+j]*s_rwp[mb*20+rr*5+j];
      #pragma unroll
      for(int i=0;i<5;i++) ab+=s_link2[mb*25+i*5+m]*s_rwp[mb*20+rr*5+i];
      s_fwd[mb*20+rr*5+m]=af;
      s_bwd[mb*20+rr*5+m]=ab;
    }
    WB();
    // M5
    if(mu<20){
      int rr=mu/5;
      float mx=-1e30f;
      #pragma unroll
      for(int m=0;m<5;m++) mx=fmaxf(mx,s_rl[mb*20+rr*5+m]);
      float s=0.f;
      #pragma unroll
      for(int m=0;m<5;m++) s+=expf(s_rl[mb*20+rr*5+m]-mx);
      float rcw=expf(s_rl[mb*20+mu]-mx)/s;
      float q0=XI(123+3*rr),q1=XI(124+3*rr),q2=XI(125+3*rr);
      float m3=fmaxf(q0,fmaxf(q1,q2));
      float e0=expf(q0-m3),e1=expf(q1-m3),e2=expf(q2-m3);
      float inv=1.f/(e0+e1+e2);
      s_rw[mb*20+mu]=(e0*s_bwd[mb*20+mu]+e1*s_fwd[mb*20+mu]+e2*rcw)*inv;
    }
    WB();
    // M6
    for(int k=mu;k<64;k+=32){
      int rr=k>>4,w=k&15;
      float a=0.f;
      #pragma unroll
      for(int m=0;m<5;m++) a+=s_rw[mb*20+rr*5+m]*s_mem2[mb*80+m*16+w];
      rvbuf[mb*64+k]=a;
    }
    for(int k=mu;k<80;k+=32) s_mem[mb*80+k]=s_mem2[mb*80+k];
    if(mu<25) s_link[mb*25+mu]=s_link2[mb*25+mu];
    else if(mu<30) s_prec[mb*5+mu-25]=s_prec2[mb*5+mu-25];
    if(mu<20) s_rwp[mb*20+mu]=s_rw[mb*20+mu];
    if(mu>=27&&mu<32){ int m=mu-27; s_wwp[mb*5+m]=s_ww[mb*5+m]; }
    __syncthreads();

    if(tt==511){
      int cb=((g*16+r)*512+tt)*576;
      if(tid<128){
        int kg=tid>>1, e=tid&1;
        U64H4 pv; pv.u=HB[2048+(kg*16+r)*2+e];
        #pragma unroll
        for(int i=0;i<4;i++){
          float x=(float)pv.h[i];
          cat[cb+kg*8+e*4+i]=__float2bfloat16(fminf(fmaxf(x,-20.f),20.f));
        }
      }
      if(tid<64) cat[cb+512+tid]=__float2bfloat16(rvbuf[r*64+tid]);
      break;
    }

    // build lr B-frags in HB[4096..4351]
    if(tid<256){
      int kg=tid>>5, rem=tid&31, b2=rem>>1, e=rem&1;
      U64H4 pk;
      #pragma unroll
      for(int i=0;i<4;i++) pk.h[i]=(f16)rvbuf[b2*64 + kg*8+e*4+i];
      HB[4096+(kg*16+b2)*2+e]=pk.u;
    }
    __syncthreads();
    // A p2: lr chunks (prefetched weights) + register-local nonlin0
    #pragma unroll
    for(int c2=0;c2<2;c2++){
      U4H8 wf; wf.u=pfA2[c2];
      f16x8 bfr=HBv[2048+(c2*4+q4)*16+lm];
      accA=__builtin_amdgcn_mfma_f32_16x16x32_f16(wf.h,bfr,accA,0,0,0);
    }
    {
      float gi=accA[0]+em0, gf=accA[1]+em1, gg=accA[2]+em2, go=accA[3]+em3;
      float c0=sigf(gf)*c0s+sigf(gi)*tanhf(gg);
      c0s=c0;
      sh_pub[(wv*4+q4)*16+lm]=(f16)(sigf(go)*tanhf(c0));
    }
    __syncthreads();
    if(tid<128){
      int ks=tid>>4, b2=tid&15;
      U64H4 pk;
      #pragma unroll
      for(int i=0;i<4;i++) pk.h[i]=sh_pub[(ks*4+i)*16+b2];
      ast64(&GX0[g*4096+pn*2048+((4*r+(ks>>1))*16+b2)*2+(ks&1)], pk.u);
    }
    PUBF(2*tt+4);      // alpha(tt+1)

    // cover2: B p1 (Wh1 chunks, PREFETCHED) on h1(tt); cat stores; prefetch B p2 frags
    f32x4 accB=(f32x4){0.f,0.f,0.f,0.f};
    #pragma unroll
    for(int c=0;c<16;c++){
      U4H8 wf; wf.u=pfB1[c];
      f16x8 bfr=HBv[1024+(c*4+q4)*16+lm];
      accB=__builtin_amdgcn_mfma_f32_16x16x32_f16(wf.h,bfr,accB,0,0,0);
    }
    uint4 pfB2[16];
    #pragma unroll
    for(int c=0;c<16;c++) pfB2[c]=PBv[((r*8+wv)*32+c)*64+l];
    {
      int cb=((g*16+r)*512+tt)*576;
      if(tid<128){
        int kg=tid>>1, e=tid&1;
        U64H4 pv; pv.u=HB[2048+(kg*16+r)*2+e];
        #pragma unroll
        for(int i=0;i<4;i++){
          float x=(float)pv.h[i];
          cat[cb+kg*8+e*4+i]=__float2bfloat16(fminf(fmaxf(x,-20.f),20.f));
        }
      }
      if(tid<64) cat[cb+512+tid]=__float2bfloat16(rvbuf[r*64+tid]);
    }

    WAITG(2*tt+4);     // alpha(tt+1)

    // B p2: stage h0(tt+1), Wi1 chunks (prefetched), register-local nonlin1
    {
      u64 s0=ald64(&GX0[g*4096+pn*2048+tid      ]);
      u64 s1=ald64(&GX0[g*4096+pn*2048+tid+512  ]);
      u64 s2=ald64(&GX0[g*4096+pn*2048+tid+1024 ]);
      u64 s3=ald64(&GX0[g*4096+pn*2048+tid+1536 ]);
      HB[tid]=s0; HB[tid+512]=s1; HB[tid+1024]=s2; HB[tid+1536]=s3;
    }
    __syncthreads();
    #pragma unroll
    for(int c=0;c<16;c++){
      U4H8 wf; wf.u=pfB2[c];
      f16x8 bfr=HBv[(c*4+q4)*16+lm];
      accB=__builtin_amdgcn_mfma_f32_16x16x32_f16(wf.h,bfr,accB,0,0,0);
    }
    // prefetch next iteration's A1 weights (in flight across nonlin/store/pub)
    #pragma unroll
    for(int c=0;c<16;c++) pfA1[c]=PAv[((r*8+wv)*18+c)*64+l];
    {
      float gi=accB[0]+b1Li, gf=accB[1]+b1Lf, gg=accB[2]+b1Lg, go=accB[3]+b1Lo;
      float c1=sigf(gf)*c1s+sigf(gi)*tanhf(gg);
      c1s=c1;
      sh_pub[(wv*4+q4)*16+lm]=(f16)(sigf(go)*tanhf(c1));
    }
    __syncthreads();
    if(tid<128){
      int ks=tid>>4, b2=tid&15;
      U64H4 pk;
      #pragma unroll
      for(int i=0;i<4;i++) pk.h[i]=sh_pub[(ks*4+i)*16+b2];
      ast64(&GX1[g*4096+pn*2048+((4*r+(ks>>1))*16+b2)*2+(ks&1)], pk.u);
    }
    PUBF(2*tt+5);      // beta(tt+1)
  }
#undef WAITG
#undef PUBF
#undef XI
#undef WB
}

// ---------------- final output GEMM (f32 out) ----------------
__global__ void __launch_bounds__(256) k_out(const bf16* __restrict__ cat,
                                             const float* __restrict__ Wc,
                                             const float* __restrict__ bc,
                                             float* __restrict__ outp){
  int t0=blockIdx.x*64, v0=blockIdx.y*64, b=blockIdx.z;
  __shared__ float As[64][33];
  __shared__ float Bs[32][65];
  int tid=threadIdx.x;
  int ti=tid>>4, vi=tid&15;
  float acc[4][4]={};
  for(int k0=0;k0<576;k0+=32){
    for(int i=tid;i<64*32;i+=256){
      int rr=i>>5,k=i&31;
      As[rr][k]=b2f(cat[(b*512+t0+rr)*576+k0+k]);
    }
    for(int i=tid;i<64*32;i+=256){
      int v=i>>5,k=i&31;
      Bs[k][v]=Wc[(v0+v)*576+k0+k];
    }
    __syncthreads();
    #pragma unroll 8
    for(int kk=0;kk<32;kk++){
      float av[4],bv[4];
      #pragma unroll
      for(int x=0;x<4;x++) av[x]=As[ti*4+x][kk];
      #pragma unroll
      for(int y=0;y<4;y++) bv[y]=Bs[kk][vi*4+y];
      #pragma unroll
      for(int x=0;x<4;x++)
        #pragma unroll
        for(int y=0;y<4;y++) acc[x][y]+=av[x]*bv[y];
    }
    __syncthreads();
  }
  #pragma unroll
  for(int y=0;y<4;y++){
    int v=v0+vi*4+y;
    float bcv=bc[v];
    #pragma unroll
    for(int x=0;x<4;x++){
      int tt=t0+ti*4+x;
      outp[(b*256+v)*512+tt]=acc[x][y]+bcv;
    }
  }
}

extern "C" void kernel_launch(void* const* d_in, const int* in_sizes, int n_in,
                              void* d_out, int out_size, void* d_ws, size_t ws_size,
                              hipStream_t stream) {
  const int*  tokens = (const int*) d_in[0];
  const void* emb    = d_in[1];
  const void* Wi0    = d_in[2];
  const void* Wh0    = d_in[3];
  const void* b0     = d_in[4];
  const void* Wi1    = d_in[5];
  const void* Wh1    = d_in[6];
  const void* b1     = d_in[7];
  const void* W_if   = d_in[8];
  const void* b_if   = d_in[9];
  const void* W_out  = d_in[10];
  const void* b_out  = d_in[11];
  const void* W_fc   = d_in[12];
  const void* b_fc   = d_in[13];

  static const int expect[14] = {64*512, 256*512, 2048*576, 2048*512, 2048,
                                 2048*512, 2048*512, 2048, 135*512, 135,
                                 512*576, 512, 256*512, 256};
  bool ok = (n_in == 14);
  if(ok) for(int i=0;i<14;i++) if(in_sizes[i]!=expect[i]) ok=false;

  int*      flags = (int*)d_ws;                   // [0]=dtype flag
  float*    embW  = (float*)d_ws + 64;            // 2048*256
  ushort_t* PA    = (ushort_t*)(embW + 524288);   // 1179648 f16 used (region 1310720; FL at +1179648)
  ushort_t* PB    = PA + 1310720;                 // 2097152 f16
  float*    Wreg  = (float*)(PB + 2097152);       // PW (73728 f16) lives here
  float*    b_ifF = Wreg + 69632;                 // 160
  float*    Wc    = b_ifF + 160;                  // 147456
  float*    bc    = Wc + 147456;                  // 256
  u64*      GX0   = (u64*)(bc + 256);             // 16384 u64 = [4 grp][2 ph][2048]
  u64*      GX1   = GX0 + 16384;                  // 16384 u64
  u64*      GXL   = GX1 + 16384;                  // 2048 u64 (unused, layout keep)
  bf16*     cat   = (bf16*)(GXL + 2048);          // 64*512*576
  unsigned* FL    = (unsigned*)(PA + 1179648);    // 64 dwords: 4 groups x 16 flags
  ushort_t* PW    = (ushort_t*)Wreg;              // 73728 f16

  size_t need = 9783168ull + 278528ull + 37748736ull;   // = 47,810,432 B
  if(!ok || ws_size < need){
    hipMemsetAsync(d_out, 0, (size_t)out_size*4, stream);
    return;
  }

  k_detect<<<dim3(1), dim3(256), 0, stream>>>(emb, flags);
  k_embW<<<dim3(2048), dim3(256), 0, stream>>>(emb, Wi0, b0, flags, embW);
  k_wpkA<<<dim3(4608), dim3(256), 0, stream>>>(Wh0, Wi0, flags, PA);
  k_wpkB<<<dim3(8192), dim3(256), 0, stream>>>(Wi1, Wh1, flags, PB);
  k_wifP<<<dim3(288), dim3(256), 0, stream>>>(W_if, b_if, flags, PW, b_ifF, FL);
  k_wc  <<<dim3(576),  dim3(256), 0, stream>>>(W_fc, W_out, b_out, b_fc, flags, Wc, bc);

  void* kargs[] = {
    (void*)&tokens, (void*)&b1, (void*)&flags,
    (void*)&embW, (void*)&PA, (void*)&PB,
    (void*)&PW, (void*)&b_ifF,
    (void*)&GX0, (void*)&GX1, (void*)&FL,
    (void*)&cat
  };
  hipLaunchCooperativeKernel((const void*)k_dnc3, dim3(64), dim3(512), kargs, 0, stream);

  k_out<<<dim3(8,4,64), dim3(256), 0, stream>>>(cat, Wc, bc, (float*)d_out);
}

// Round 10
// 11745.770 us; speedup vs baseline: 1.6462x; 1.6462x over previous
//
#include <hip/hip_runtime.h>
#include <hip/hip_bf16.h>

typedef __hip_bfloat16 bf16;
typedef _Float16 f16;
typedef _Float16 f16x8 __attribute__((ext_vector_type(8)));
typedef float f32x4 __attribute__((ext_vector_type(4)));
typedef unsigned long long u64;
typedef unsigned short ushort_t;

__device__ __forceinline__ float b2f(bf16 x){ return __bfloat162float(x); }
__device__ __forceinline__ float sigf(float x){ return 1.f/(1.f+expf(-x)); }
__device__ __forceinline__ float splus(float x){ return fmaxf(x,0.f)+log1pf(expf(-fabsf(x))); }
__device__ __forceinline__ float ldf(const void* p, int i, int isf32){
  return isf32 ? ((const float*)p)[i] : __bfloat162float(((const bf16*)p)[i]);
}
// agent-scope coherent ops (bypass per-XCD L2). Proven cross-XCD coherent, no fences.
__device__ __forceinline__ void ast64(u64* p, u64 v){ __hip_atomic_store(p, v, __ATOMIC_RELAXED, __HIP_MEMORY_SCOPE_AGENT); }
__device__ __forceinline__ u64 ald64(u64* p){ return __hip_atomic_load(p, __ATOMIC_RELAXED, __HIP_MEMORY_SCOPE_AGENT); }
__device__ __forceinline__ void ast32(unsigned* p, unsigned v){ __hip_atomic_store(p, v, __ATOMIC_RELAXED, __HIP_MEMORY_SCOPE_AGENT); }
__device__ __forceinline__ unsigned ald32(unsigned* p){ return __hip_atomic_load(p, __ATOMIC_RELAXED, __HIP_MEMORY_SCOPE_AGENT); }

union U4H8 { uint4 u; f16x8 h; };
union U64H4 { u64 u; f16 h[4]; };
union H16 { f16 h; ushort_t s; };

// ---------------- dtype detect ----------------
__global__ void k_detect(const void* __restrict__ emb, int* __restrict__ flag){
  __shared__ float mx[256];
  int tid=threadIdx.x;
  float v = fabsf(__bfloat162float(((const bf16*)emb)[tid]));
  mx[tid]=v; __syncthreads();
  for(int s=128;s>0;s>>=1){ if(tid<s) mx[tid]=fmaxf(mx[tid],mx[tid+s]); __syncthreads(); }
  if(tid==0){ flag[0] = (mx[0]>1000.f) ? 1 : 0; flag[1] = 0; }
}

// ---------------- setup ----------------
// embW[row][v] = b0[row] + sum_k emb[v][k]*Wi0[row][k]   (row-major [2048][256])
__global__ void k_embW(const void* __restrict__ emb, const void* __restrict__ Wi0,
                       const void* __restrict__ b0,
                       const int* __restrict__ flags, float* __restrict__ embW){
  int f=flags[0];
  int row = blockIdx.x;
  __shared__ float w[512];
  for(int k=threadIdx.x;k<512;k+=256) w[k]=ldf(Wi0,row*576+k,f);
  __syncthreads();
  int v = threadIdx.x;
  float acc=ldf(b0,row,f);
  #pragma unroll 4
  for(int k=0;k<512;k++) acc += ldf(emb,v*512+k,f)*w[k];
  embW[row*256+v]=acc;
}

// ---- layer-0 sliced prepack, TRANSPOSED rows (row-in-tile = dd*4+G) so one
// f32x4 acc holds all 4 gates of one dim (register-local nonlinearity).
__global__ void k_wpkA(const void* __restrict__ Wh0, const void* __restrict__ Wi0,
                       const int* __restrict__ flags, ushort_t* __restrict__ PA){
  int f=flags[0];
  int idx=blockIdx.x*256+threadIdx.x;
  if(idx>=1179648) return;
  int j=idx&7, l=(idx>>3)&63, rest=idx>>9;
  int c=rest%18, t2=rest/18, w=t2&7, r=t2>>3;
  int tr=l&15, q4=l>>4;
  int G=tr&3, dd=tr>>2;
  int row=G*512 + r*32 + w*4 + dd;
  int k=c*32 + q4*8 + j;
  float val = (k<512)? ldf(Wh0,row*512+k,f) : ldf(Wi0,row*576+k,f);
  H16 hx; hx.h=(f16)val; PA[idx]=hx.s;
}
// ---- layer-1 sliced prepack, transposed ----
__global__ void k_wpkB(const void* __restrict__ Wi1, const void* __restrict__ Wh1,
                       const int* __restrict__ flags, ushort_t* __restrict__ PB){
  int f=flags[0];
  int idx=blockIdx.x*256+threadIdx.x;
  if(idx>=2097152) return;
  int j=idx&7, l=(idx>>3)&63, rest=idx>>9;
  int c=rest&31, t2=rest>>5, w=t2&7, r=t2>>3;
  int tr=l&15, q4=l>>4;
  int G=tr&3, dd=tr>>2;
  int row=G*512 + r*32 + w*4 + dd;
  int k=c*32 + q4*8 + j;
  float val = (k<512)? ldf(Wi1,row*512+k,f) : ldf(Wh1,row*512+k-512,f);
  H16 hx; hx.h=(f16)val; PB[idx]=hx.s;
}

// W_if prepack into MFMA A-frags; zeroes FL; loads b_ifF.
__global__ void k_wifP(const void* __restrict__ W_if, const void* __restrict__ b_if,
                       const int* __restrict__ flags,
                       ushort_t* __restrict__ PW, float* __restrict__ b_ifF,
                       unsigned* __restrict__ FLz){
  int f=flags[0];
  int idx=blockIdx.x*256+threadIdx.x;
  if(idx<73728){
    int j=idx&7, l=(idx>>3)&63, c=(idx>>9)&15, tile=idx>>13;
    int row=tile*16+(l&15);
    int k=c*32+(l>>4)*8+j;
    float val=(row<135)? ldf(W_if,row*512+k,f) : 0.f;
    H16 hx; hx.h=(f16)val; PW[idx]=hx.s;
  }
  if(idx<64) FLz[idx]=0u;
  if(idx<135) b_ifF[idx]=ldf(b_if,idx,f);
}

__global__ void k_wc(const void* __restrict__ W_fc, const void* __restrict__ W_out,
                     const void* __restrict__ b_out, const void* __restrict__ b_fc,
                     const int* __restrict__ flags,
                     float* __restrict__ Wc, float* __restrict__ bc){
  int f=flags[0];
  int idx=blockIdx.x*256+threadIdx.x;
  int v=idx/576, j=idx-v*576;
  float acc=0.f;
  #pragma unroll 4
  for(int d=0;d<512;d++) acc += ldf(W_fc,v*512+d,f)*ldf(W_out,d*576+j,f);
  Wc[idx]=acc;
  if(j==0){
    float a=ldf(b_fc,v,f);
    for(int d=0;d<512;d++) a += ldf(W_fc,v*512+d,f)*ldf(b_out,d,f);
    bc[v]=a;
  }
}

// ---------------- grouped recurrence (2-hop) + hop-covering prefetch ----------------
// 4 groups x 16 blocks; block (g,r) owns dims [32r,32r+32); L2-resident slices.
// vs round 9: __launch_bounds__(512,2) (documented min-waves-per-EU knob ->
// 256-VGPR budget at unchanged 1 block/CU) and the prefetch set trimmed to
// DISJOINT live ranges that fit: pfP3 (covers beta hop), pfB2 (covers alpha
// hop, round-7-proven), pfA2. A1/cover2/wave0-P3 stream inline (round-8 form).
__global__ void __launch_bounds__(512, 2) k_dnc3(
    const int* __restrict__ tokens, const void* __restrict__ b1, const int* __restrict__ flags,
    const float* __restrict__ embW, const ushort_t* __restrict__ PA, const ushort_t* __restrict__ PB,
    const ushort_t* __restrict__ PW, const float* __restrict__ b_ifF,
    u64* GX0, u64* GX1, unsigned* FL,
    bf16* __restrict__ cat)
{
  const int bid = blockIdx.x;
  const int g   = bid>>4, r = bid&15;
  const int tid = threadIdx.x;
  const int wv  = tid>>6, l = tid&63;
  const int lm  = l&15,  q4 = l>>4;
  const int mb  = tid>>5, mu = tid&31;     // machinery mapping (batch, slot)
  const int f32i = flags[0];

  __shared__ __align__(16) u64 HB[4352];   // [0..2047] h0 | [2048..4095] h1 | [4096..4351] lr frags
  __shared__ f16  sh_pub[512];
  __shared__ int  tokL[16];
  __shared__ float b_ifL[144];
  __shared__ float xis2[16*149];
  __shared__ float s_pre[16*112];          // precomputed transcendentals per batch
  __shared__ float s_mem[1280], s_mem2[1280], s_link[400], s_link2[400];
  __shared__ float s_prec[80], s_prec2[80], s_rwp[320], s_rw[320];
  __shared__ float s_wwp[80], s_ww[80], s_usage[80], s_wl[80];
  __shared__ float s_rl[320], s_fwd[320], s_bwd[320], s_wsum[16];
  __shared__ float rvbuf[1024];

#define WAITG(TGT) do{ if(tid<16){ unsigned _tg=(unsigned)(TGT); int _wd=0; \
    while(ald32(&FL[g*16+tid]) < _tg && _wd<50000000){ __builtin_amdgcn_s_sleep(1); _wd++; } } \
  __syncthreads(); }while(0)
#define PUBF(VAL) do{ __syncthreads(); \
  if(tid==0) ast32(&FL[g*16+r],(unsigned)(VAL)); }while(0)
#define XI(i) xis2[mb*149+(i)]
#define WB() __builtin_amdgcn_wave_barrier()

  const f16x8* HBv=(const f16x8*)HB;
  const uint4* PAv=(const uint4*)PA;
  const uint4* PBv=(const uint4*)PB;
  const uint4* PWv=(const uint4*)PW;

  // per-thread biases for (dim1 = r*32+wv*4+q4), 4 gates
  const int dim1 = r*32 + wv*4 + q4;
  const float b1Li=ldf(b1,dim1,f32i), b1Lf=ldf(b1,512+dim1,f32i),
              b1Lg=ldf(b1,1024+dim1,f32i), b1Lo=ldf(b1,1536+dim1,f32i);

  if(tid<144) b_ifL[tid]=(tid<135)? b_ifF[tid] : 0.f;
  for(int i=tid;i<1280;i+=512) s_mem[i]=0.f;
  for(int i=tid;i<400;i+=512) s_link[i]=0.f;
  for(int i=tid;i<320;i+=512) s_rwp[i]=0.f;
  if(tid<80){ s_prec[tid]=0.f; s_wwp[tid]=0.f; s_usage[tid]=0.f; }
  float c0s=0.f, c1s=0.f;

  // ---- prologue t=0: h0(0)=f(em(0)); h1(0)=g(h0(0)) ----
  if(tid<16) tokL[tid]=tokens[(g*16+tid)*512];
  __syncthreads();
  {
    int tok=tokL[lm];
    float ei=embW[dim1*256+tok];
    float eg=embW[262144+dim1*256+tok];
    float eo=embW[393216+dim1*256+tok];
    c0s = sigf(ei)*tanhf(eg);
    sh_pub[(wv*4+q4)*16+lm]=(f16)(sigf(eo)*tanhf(c0s));
  }
  __syncthreads();
  if(tid<128){
    int ks=tid>>4, b2=tid&15;
    U64H4 pk;
    #pragma unroll
    for(int i=0;i<4;i++) pk.h[i]=sh_pub[(ks*4+i)*16+b2];
    ast64(&GX0[g*4096+((4*r+(ks>>1))*16+b2)*2+(ks&1)], pk.u);
  }
  PUBF(2u);            // alpha(0)
  WAITG(2u);
  {
    u64 s0=ald64(&GX0[g*4096+tid      ]);
    u64 s1=ald64(&GX0[g*4096+tid+512  ]);
    u64 s2=ald64(&GX0[g*4096+tid+1024 ]);
    u64 s3=ald64(&GX0[g*4096+tid+1536 ]);
    HB[tid]=s0; HB[tid+512]=s1; HB[tid+1024]=s2; HB[tid+1536]=s3;
  }
  __syncthreads();
  {
    f32x4 acc1=(f32x4){0.f,0.f,0.f,0.f};
    #pragma unroll
    for(int c=0;c<16;c++){
      U4H8 wf; wf.u=PBv[((r*8+wv)*32+c)*64+l];
      f16x8 bfr=HBv[(c*4+q4)*16+lm];
      acc1=__builtin_amdgcn_mfma_f32_16x16x32_f16(wf.h,bfr,acc1,0,0,0);
    }
    float gi=acc1[0]+b1Li, gg=acc1[2]+b1Lg, go=acc1[3]+b1Lo;
    c1s=sigf(gi)*tanhf(gg);
    sh_pub[(wv*4+q4)*16+lm]=(f16)(sigf(go)*tanhf(c1s));
  }
  __syncthreads();
  if(tid<128){
    int ks=tid>>4, b2=tid&15;
    U64H4 pk;
    #pragma unroll
    for(int i=0;i<4;i++) pk.h[i]=sh_pub[(ks*4+i)*16+b2];
    ast64(&GX1[g*4096+((4*r+(ks>>1))*16+b2)*2+(ks&1)], pk.u);
  }
  PUBF(3u);            // beta(0)

  // ---- main loop ----
  for(int tt=0;tt<512;tt++){
    const int p=tt&1, pn=p^1;

    // cover1: A p1 (16 chunks, inline-streamed weights) on h0(tt) in HB[0..2047]
    f32x4 accA=(f32x4){0.f,0.f,0.f,0.f};
    #pragma unroll
    for(int c=0;c<16;c++){
      U4H8 wf; wf.u=PAv[((r*8+wv)*18+c)*64+l];
      f16x8 bfr=HBv[(c*4+q4)*16+lm];
      accA=__builtin_amdgcn_mfma_f32_16x16x32_f16(wf.h,bfr,accA,0,0,0);
    }
    // prefetch em(tt+1), A2 lr-frag weights, and P3 W_if frags (hop-covered)
    float em0,em1,em2,em3;
    {
      int tn=(tt<511)?tt+1:511;
      int tok=tokens[(g*16+lm)*512+tn];
      em0=embW[dim1*256+tok]; em1=embW[131072+dim1*256+tok];
      em2=embW[262144+dim1*256+tok]; em3=embW[393216+dim1*256+tok];
    }
    uint4 pfA2[2];
    #pragma unroll
    for(int c2=0;c2<2;c2++) pfA2[c2]=PAv[((r*8+wv)*18+16+c2)*64+l];
    uint4 pfP3[16];
    #pragma unroll
    for(int cc=0;cc<16;cc++) pfP3[cc]=PWv[(wv*16+cc)*64+l];

    WAITG(2*tt+3);     // beta(tt)

    // stage h1(tt) -> HB[2048..4095]
    {
      u64 s0=ald64(&GX1[g*4096+p*2048+tid      ]);
      u64 s1=ald64(&GX1[g*4096+p*2048+tid+512  ]);
      u64 s2=ald64(&GX1[g*4096+p*2048+tid+1024 ]);
      u64 s3=ald64(&GX1[g*4096+p*2048+tid+1536 ]);
      HB[2048+tid]=s0; HB[2048+tid+512]=s1; HB[2048+tid+1024]=s2; HB[2048+tid+1536]=s3;
    }
    __syncthreads();

    // ====== P3(tt): xi = W_if @ h1 via MFMA (prefetched weights) ======
    {
      f32x4 xa=(f32x4){0.f,0.f,0.f,0.f};
      #pragma unroll
      for(int cc=0;cc<16;cc++){
        U4H8 t4; t4.u=pfP3[cc];
        f16x8 bfr=HBv[1024+(cc*4+q4)*16+lm];
        xa=__builtin_amdgcn_mfma_f32_16x16x32_f16(t4.h,bfr,xa,0,0,0);
      }
      #pragma unroll
      for(int reg=0;reg<4;reg++){
        int row=wv*16+q4*4+reg;
        xis2[lm*149+row]=xa[reg]+b_ifL[row];
      }
      if(wv==0){
        f32x4 xb=(f32x4){0.f,0.f,0.f,0.f};
        #pragma unroll
        for(int cc=0;cc<16;cc++){
          U4H8 t4; t4.u=PWv[(128+cc)*64+l];
          f16x8 bfr=HBv[1024+(cc*4+q4)*16+lm];
          xb=__builtin_amdgcn_mfma_f32_16x16x32_f16(t4.h,bfr,xb,0,0,0);
        }
        #pragma unroll
        for(int reg=0;reg<4;reg++){
          int row=128+q4*4+reg;
          xis2[lm*149+row]=xb[reg]+b_ifL[row];
        }
      }
    }
    __syncthreads();

    // ====== machinery (wave-local per batch, half-wave = 32 lanes) ======
    if(mu<16){
      s_pre[mb*112+mu]    =tanhf(XI(68+mu));
      s_pre[mb*112+16+mu] =sigf (XI(85+mu));
      s_pre[mb*112+32+mu] =tanhf(XI(101+mu));
    }
    s_pre[mb*112+48+mu]   =tanhf(XI(mu));
    s_pre[mb*112+48+32+mu]=tanhf(XI(32+mu));
    WB();
    // M1
    if(mu<5){
      int m=mu;
      float u=s_usage[mb*5+m]+(1.f-s_usage[mb*5+m])*s_wwp[mb*5+m];
      float psi=1.f;
      #pragma unroll
      for(int rr=0;rr<4;rr++) psi *= 1.f - sigf(XI(117+rr))*s_rwp[mb*20+rr*5+m];
      u*=psi; s_usage[mb*5+m]=u;
      float nm=0.f,dt=0.f,nk=0.f;
      #pragma unroll
      for(int w=0;w<16;w++){
        float mv=s_mem[mb*80+m*16+w], kv=s_pre[mb*112+w];
        nm+=mv*mv; dt+=mv*kv; nk+=kv*kv;
      }
      float sim=dt/((sqrtf(nm)+1e-6f)*(sqrtf(nk)+1e-6f));
      s_wl[mb*5+m]=sim*splus(XI(84));
    }
    WB();
    // M2a
    if(mu<5){
      int m=mu;
      float mx=s_wl[mb*5];
      #pragma unroll
      for(int j=1;j<5;j++) mx=fmaxf(mx,s_wl[mb*5+j]);
      float e=expf(s_wl[mb*5+m]-mx);
      float u=1e-6f+(1.f-1e-6f)*s_usage[mb*5+m];
      s_rl [mb*20+m]=u;   // scratch (overwritten by M4)
      s_bwd[mb*20+m]=e;   // scratch (overwritten by M4)
    }
    WB();
    // M2b: stable-rank allocation
    if(mu<5){
      int m=mu;
      float u=s_rl[mb*20+m], e=s_bwd[mb*20+m];
      float s=0.f, prod=1.f;
      #pragma unroll
      for(int j=0;j<5;j++){
        s+=s_bwd[mb*20+j];
        float uj=s_rl[mb*20+j];
        if(uj<u || (uj==u && j<m)) prod*=uj;
      }
      float wcw=e/s;
      float alloc=(1.f-u)*prod;
      float ag=sigf(XI(121)), wgg=sigf(XI(122));
      s_ww[mb*5+m]=wgg*(ag*alloc+(1.f-ag)*wcw);
    }
    WB();
    if(mu==0){
      float ws=0.f;
      #pragma unroll
      for(int m=0;m<5;m++) ws+=s_ww[mb*5+m];
      s_wsum[mb]=ws;
    }
    WB();
    // M3
    for(int k=mu;k<80;k+=32){
      int m=k>>4,w=k&15;
      float er=s_pre[mb*112+16+w], wv2=s_pre[mb*112+32+w];
      float w_=s_ww[mb*5+m];
      s_mem2[mb*80+k]=s_mem[mb*80+k]*(1.f-w_*er)+w_*wv2;
    }
    if(mu<25){
      int i=mu/5, j=mu-5*i;
      s_link2[mb*25+mu]=(i==j)?0.f:((1.f-s_ww[mb*5+i]-s_ww[mb*5+j])*s_link[mb*25+mu]+s_ww[mb*5+i]*s_prec[mb*5+j]);
    } else if(mu<30){
      int j=mu-25;
      s_prec2[mb*5+j]=(1.f-s_wsum[mb])*s_prec[mb*5+j]+s_ww[mb*5+j];
    }
    WB();
    // M4
    if(mu<20){
      int rr=mu/5, m=mu-5*rr;
      float nm=0.f,dt=0.f,nk=0.f;
      #pragma unroll
      for(int w=0;w<16;w++){
        float mv=s_mem2[mb*80+m*16+w], kv=s_pre[mb*112+48+rr*16+w];
        nm+=mv*mv; dt+=mv*kv; nk+=kv*kv;
      }
      float sim=dt/((sqrtf(nm)+1e-6f)*(sqrtf(nk)+1e-6f));
      s_rl[mb*20+mu]=sim*splus(XI(64+rr));
      float af=0.f, ab=0.f;
      #pragma unroll
      for(int j=0;j<5;j++) af+=s_link2[mb*25+m*5+j]*s_rwp[mb*20+rr*5+j];
      #pragma unroll
      for(int i=0;i<5;i++) ab+=s_link2[mb*25+i*5+m]*s_rwp[mb*20+rr*5+i];
      s_fwd[mb*20+rr*5+m]=af;
      s_bwd[mb*20+rr*5+m]=ab;
    }
    WB();
    // M5
    if(mu<20){
      int rr=mu/5;
      float mx=-1e30f;
      #pragma unroll
      for(int m=0;m<5;m++) mx=fmaxf(mx,s_rl[mb*20+rr*5+m]);
      float s=0.f;
      #pragma unroll
      for(int m=0;m<5;m++) s+=expf(s_rl[mb*20+rr*5+m]-mx);
      float rcw=expf(s_rl[mb*20+mu]-mx)/s;
      float q0=XI(123+3*rr),q1=XI(124+3*rr),q2=XI(125+3*rr);
      float m3=fmaxf(q0,fmaxf(q1,q2));
      float e0=expf(q0-m3),e1=expf(q1-m3),e2=expf(q2-m3);
      float inv=1.f/(e0+e1+e2);
      s_rw[mb*20+mu]=(e0*s_bwd[mb*20+mu]+e1*s_fwd[mb*20+mu]+e2*rcw)*inv;
    }
    WB();
    // M6
    for(int k=mu;k<64;k+=32){
      int rr=k>>4,w=k&15;
      float a=0.f;
      #pragma unroll
      for(int m=0;m<5;m++) a+=s_rw[mb*20+rr*5+m]*s_mem2[mb*80+m*16+w];
      rvbuf[mb*64+k]=a;
    }
    for(int k=mu;k<80;k+=32) s_mem[mb*80+k]=s_mem2[mb*80+k];
    if(mu<25) s_link[mb*25+mu]=s_link2[mb*25+mu];
    else if(mu<30) s_prec[mb*5+mu-25]=s_prec2[mb*5+mu-25];
    if(mu<20) s_rwp[mb*20+mu]=s_rw[mb*20+mu];
    if(mu>=27&&mu<32){ int m=mu-27; s_wwp[mb*5+m]=s_ww[mb*5+m]; }
    __syncthreads();

    if(tt==511){
      int cb=((g*16+r)*512+tt)*576;
      if(tid<128){
        int kg=tid>>1, e=tid&1;
        U64H4 pv; pv.u=HB[2048+(kg*16+r)*2+e];
        #pragma unroll
        for(int i=0;i<4;i++){
          float x=(float)pv.h[i];
          cat[cb+kg*8+e*4+i]=__float2bfloat16(fminf(fmaxf(x,-20.f),20.f));
        }
      }
      if(tid<64) cat[cb+512+tid]=__float2bfloat16(rvbuf[r*64+tid]);
      break;
    }

    // build lr B-frags in HB[4096..4351]
    if(tid<256){
      int kg=tid>>5, rem=tid&31, b2=rem>>1, e=rem&1;
      U64H4 pk;
      #pragma unroll
      for(int i=0;i<4;i++) pk.h[i]=(f16)rvbuf[b2*64 + kg*8+e*4+i];
      HB[4096+(kg*16+b2)*2+e]=pk.u;
    }
    __syncthreads();
    // A p2: lr chunks (prefetched weights) + register-local nonlin0
    #pragma unroll
    for(int c2=0;c2<2;c2++){
      U4H8 wf; wf.u=pfA2[c2];
      f16x8 bfr=HBv[2048+(c2*4+q4)*16+lm];
      accA=__builtin_amdgcn_mfma_f32_16x16x32_f16(wf.h,bfr,accA,0,0,0);
    }
    {
      float gi=accA[0]+em0, gf=accA[1]+em1, gg=accA[2]+em2, go=accA[3]+em3;
      float c0=sigf(gf)*c0s+sigf(gi)*tanhf(gg);
      c0s=c0;
      sh_pub[(wv*4+q4)*16+lm]=(f16)(sigf(go)*tanhf(c0));
    }
    __syncthreads();
    if(tid<128){
      int ks=tid>>4, b2=tid&15;
      U64H4 pk;
      #pragma unroll
      for(int i=0;i<4;i++) pk.h[i]=sh_pub[(ks*4+i)*16+b2];
      ast64(&GX0[g*4096+pn*2048+((4*r+(ks>>1))*16+b2)*2+(ks&1)], pk.u);
    }
    PUBF(2*tt+4);      // alpha(tt+1)

    // cover2: B p1 (Wh1 chunks, inline-streamed) on h1(tt); cat stores;
    // prefetch B p2 frags (consumed after the alpha wait)
    f32x4 accB=(f32x4){0.f,0.f,0.f,0.f};
    #pragma unroll
    for(int c=16;c<32;c++){
      U4H8 wf; wf.u=PBv[((r*8+wv)*32+c)*64+l];
      f16x8 bfr=HBv[1024+((c-16)*4+q4)*16+lm];
      accB=__builtin_amdgcn_mfma_f32_16x16x32_f16(wf.h,bfr,accB,0,0,0);
    }
    uint4 pfB2[16];
    #pragma unroll
    for(int c=0;c<16;c++) pfB2[c]=PBv[((r*8+wv)*32+c)*64+l];
    {
      int cb=((g*16+r)*512+tt)*576;
      if(tid<128){
        int kg=tid>>1, e=tid&1;
        U64H4 pv; pv.u=HB[2048+(kg*16+r)*2+e];
        #pragma unroll
        for(int i=0;i<4;i++){
          float x=(float)pv.h[i];
          cat[cb+kg*8+e*4+i]=__float2bfloat16(fminf(fmaxf(x,-20.f),20.f));
        }
      }
      if(tid<64) cat[cb+512+tid]=__float2bfloat16(rvbuf[r*64+tid]);
    }

    WAITG(2*tt+4);     // alpha(tt+1)

    // B p2: stage h0(tt+1), Wi1 chunks (prefetched), register-local nonlin1
    {
      u64 s0=ald64(&GX0[g*4096+pn*2048+tid      ]);
      u64 s1=ald64(&GX0[g*4096+pn*2048+tid+512  ]);
      u64 s2=ald64(&GX0[g*4096+pn*2048+tid+1024 ]);
      u64 s3=ald64(&GX0[g*4096+pn*2048+tid+1536 ]);
      HB[tid]=s0; HB[tid+512]=s1; HB[tid+1024]=s2; HB[tid+1536]=s3;
    }
    __syncthreads();
    #pragma unroll
    for(int c=0;c<16;c++){
      U4H8 wf; wf.u=pfB2[c];
      f16x8 bfr=HBv[(c*4+q4)*16+lm];
      accB=__builtin_amdgcn_mfma_f32_16x16x32_f16(wf.h,bfr,accB,0,0,0);
    }
    {
      float gi=accB[0]+b1Li, gf=accB[1]+b1Lf, gg=accB[2]+b1Lg, go=accB[3]+b1Lo;
      float c1=sigf(gf)*c1s+sigf(gi)*tanhf(gg);
      c1s=c1;
      sh_pub[(wv*4+q4)*16+lm]=(f16)(sigf(go)*tanhf(c1));
    }
    __syncthreads();
    if(tid<128){
      int ks=tid>>4, b2=tid&15;
      U64H4 pk;
      #pragma unroll
      for(int i=0;i<4;i++) pk.h[i]=sh_pub[(ks*4+i)*16+b2];
      ast64(&GX1[g*4096+pn*2048+((4*r+(ks>>1))*16+b2)*2+(ks&1)], pk.u);
    }
    PUBF(2*tt+5);      // beta(tt+1)
  }
#undef WAITG
#undef PUBF
#undef XI
#undef WB
}

// ---------------- final output GEMM (f32 out) ----------------
__global__ void __launch_bounds__(256) k_out(const bf16* __restrict__ cat,
                                             const float* __restrict__ Wc,
                                             const float* __restrict__ bc,
                                             float* __restrict__ outp){
  int t0=blockIdx.x*64, v0=blockIdx.y*64, b=blockIdx.z;
  __shared__ float As[64][33];
  __shared__ float Bs[32][65];
  int tid=threadIdx.x;
  int ti=tid>>4, vi=tid&15;
  float acc[4][4]={};
  for(int k0=0;k0<576;k0+=32){
    for(int i=tid;i<64*32;i+=256){
      int rr=i>>5,k=i&31;
      As[rr][k]=b2f(cat[(b*512+t0+rr)*576+k0+k]);
    }
    for(int i=tid;i<64*32;i+=256){
      int v=i>>5,k=i&31;
      Bs[k][v]=Wc[(v0+v)*576+k0+k];
    }
    __syncthreads();
    #pragma unroll 8
    for(int kk=0;kk<32;kk++){
      float av[4],bv[4];
      #pragma unroll
      for(int x=0;x<4;x++) av[x]=As[ti*4+x][kk];
      #pragma unroll
      for(int y=0;y<4;y++) bv[y]=Bs[kk][vi*4+y];
      #pragma unroll
      for(int x=0;x<4;x++)
        #pragma unroll
        for(int y=0;y<4;y++) acc[x][y]+=av[x]*bv[y];
    }
    __syncthreads();
  }
  #pragma unroll
  for(int y=0;y<4;y++){
    int v=v0+vi*4+y;
    float bcv=bc[v];
    #pragma unroll
    for(int x=0;x<4;x++){
      int tt=t0+ti*4+x;
      outp[(b*256+v)*512+tt]=acc[x][y]+bcv;
    }
  }
}

extern "C" void kernel_launch(void* const* d_in, const int* in_sizes, int n_in,
                              void* d_out, int out_size, void* d_ws, size_t ws_size,
                              hipStream_t stream) {
  const int*  tokens = (const int*) d_in[0];
  const void* emb    = d_in[1];
  const void* Wi0    = d_in[2];
  const void* Wh0    = d_in[3];
  const void* b0     = d_in[4];
  const void* Wi1    = d_in[5];
  const void* Wh1    = d_in[6];
  const void* b1     = d_in[7];
  const void* W_if   = d_in[8];
  const void* b_if   = d_in[9];
  const void* W_out  = d_in[10];
  const void* b_out  = d_in[11];
  const void* W_fc   = d_in[12];
  const void* b_fc   = d_in[13];

  static const int expect[14] = {64*512, 256*512, 2048*576, 2048*512, 2048,
                                 2048*512, 2048*512, 2048, 135*512, 135,
                                 512*576, 512, 256*512, 256};
  bool ok = (n_in == 14);
  if(ok) for(int i=0;i<14;i++) if(in_sizes[i]!=expect[i]) ok=false;

  int*      flags = (int*)d_ws;                   // [0]=dtype flag
  float*    embW  = (float*)d_ws + 64;            // 2048*256
  ushort_t* PA    = (ushort_t*)(embW + 524288);   // 1179648 f16 used (region 1310720; FL at +1179648)
  ushort_t* PB    = PA + 1310720;                 // 2097152 f16
  float*    Wreg  = (float*)(PB + 2097152);       // PW (73728 f16) lives here
  float*    b_ifF = Wreg + 69632;                 // 160
  float*    Wc    = b_ifF + 160;                  // 147456
  float*    bc    = Wc + 147456;                  // 256
  u64*      GX0   = (u64*)(bc + 256);             // 16384 u64 = [4 grp][2 ph][2048]
  u64*      GX1   = GX0 + 16384;                  // 16384 u64
  u64*      GXL   = GX1 + 16384;                  // 2048 u64 (unused, layout keep)
  bf16*     cat   = (bf16*)(GXL + 2048);          // 64*512*576
  unsigned* FL    = (unsigned*)(PA + 1179648);    // 64 dwords: 4 groups x 16 flags
  ushort_t* PW    = (ushort_t*)Wreg;              // 73728 f16

  size_t need = 9783168ull + 278528ull + 37748736ull;   // = 47,810,432 B
  if(!ok || ws_size < need){
    hipMemsetAsync(d_out, 0, (size_t)out_size*4, stream);
    return;
  }

  k_detect<<<dim3(1), dim3(256), 0, stream>>>(emb, flags);
  k_embW<<<dim3(2048), dim3(256), 0, stream>>>(emb, Wi0, b0, flags, embW);
  k_wpkA<<<dim3(4608), dim3(256), 0, stream>>>(Wh0, Wi0, flags, PA);
  k_wpkB<<<dim3(8192), dim3(256), 0, stream>>>(Wi1, Wh1, flags, PB);
  k_wifP<<<dim3(288), dim3(256), 0, stream>>>(W_if, b_if, flags, PW, b_ifF, FL);
  k_wc  <<<dim3(576),  dim3(256), 0, stream>>>(W_fc, W_out, b_out, b_fc, flags, Wc, bc);

  void* kargs[] = {
    (void*)&tokens, (void*)&b1, (void*)&flags,
    (void*)&embW, (void*)&PA, (void*)&PB,
    (void*)&PW, (void*)&b_ifF,
    (void*)&GX0, (void*)&GX1, (void*)&FL,
    (void*)&cat
  };
  hipLaunchCooperativeKernel((const void*)k_dnc3, dim3(64), dim3(512), kargs, 0, stream);

  k_out<<<dim3(8,4,64), dim3(256), 0, stream>>>(cat, Wc, bc, (float*)d_out);
}

// Round 11
// 11268.472 us; speedup vs baseline: 1.7159x; 1.0424x over previous
//
#include <hip/hip_runtime.h>
#include <hip/hip_bf16.h>

typedef __hip_bfloat16 bf16;
typedef _Float16 f16;
typedef _Float16 f16x8 __attribute__((ext_vector_type(8)));
typedef float f32x4 __attribute__((ext_vector_type(4)));
typedef unsigned long long u64;
typedef unsigned short ushort_t;

__device__ __forceinline__ float b2f(bf16 x){ return __bfloat162float(x); }
__device__ __forceinline__ float sigf(float x){ return 1.f/(1.f+expf(-x)); }
__device__ __forceinline__ float splus(float x){ return fmaxf(x,0.f)+log1pf(expf(-fabsf(x))); }
__device__ __forceinline__ float ldf(const void* p, int i, int isf32){
  return isf32 ? ((const float*)p)[i] : __bfloat162float(((const bf16*)p)[i]);
}
// agent-scope coherent ops (bypass per-XCD L2). Proven cross-XCD coherent, no fences.
__device__ __forceinline__ void ast64(u64* p, u64 v){ __hip_atomic_store(p, v, __ATOMIC_RELAXED, __HIP_MEMORY_SCOPE_AGENT); }
__device__ __forceinline__ u64 ald64(u64* p){ return __hip_atomic_load(p, __ATOMIC_RELAXED, __HIP_MEMORY_SCOPE_AGENT); }
__device__ __forceinline__ void ast32(unsigned* p, unsigned v){ __hip_atomic_store(p, v, __ATOMIC_RELAXED, __HIP_MEMORY_SCOPE_AGENT); }
__device__ __forceinline__ unsigned ald32(unsigned* p){ return __hip_atomic_load(p, __ATOMIC_RELAXED, __HIP_MEMORY_SCOPE_AGENT); }

union U4H8 { uint4 u; f16x8 h; };
union U64H4 { u64 u; f16 h[4]; };
union H16 { f16 h; ushort_t s; };

// ---------------- dtype detect ----------------
__global__ void k_detect(const void* __restrict__ emb, int* __restrict__ flag){
  __shared__ float mx[256];
  int tid=threadIdx.x;
  float v = fabsf(__bfloat162float(((const bf16*)emb)[tid]));
  mx[tid]=v; __syncthreads();
  for(int s=128;s>0;s>>=1){ if(tid<s) mx[tid]=fmaxf(mx[tid],mx[tid+s]); __syncthreads(); }
  if(tid==0){ flag[0] = (mx[0]>1000.f) ? 1 : 0; flag[1] = 0; }
}

// ---------------- setup ----------------
// TILED embW: embW[row][v] = b0[row] + sum_k emb[v][k]*Wi0[row][k]
// C[2048,256] = Wi0[2048,512(of 576)] @ emb^T[512,256]. 64x64 tiles, k_out pattern.
// (Old per-block scalar version re-read all of emb per block: ~1GB traffic.)
__global__ void __launch_bounds__(256) k_embW(const void* __restrict__ emb, const void* __restrict__ Wi0,
                       const void* __restrict__ b0,
                       const int* __restrict__ flags, float* __restrict__ embW){
  int f=flags[0];
  int r0=blockIdx.x*64, v0=blockIdx.y*64;
  __shared__ float As[64][33];
  __shared__ float Bs[32][65];
  int tid=threadIdx.x;
  int ti=tid>>4, vi=tid&15;
  float acc[4][4]={};
  for(int k0=0;k0<512;k0+=32){
    for(int i=tid;i<64*32;i+=256){
      int rr=i>>5,k=i&31;
      As[rr][k]=ldf(Wi0,(r0+rr)*576+k0+k,f);
    }
    for(int i=tid;i<64*32;i+=256){
      int v=i>>5,k=i&31;
      Bs[k][v]=ldf(emb,(v0+v)*512+k0+k,f);
    }
    __syncthreads();
    #pragma unroll 8
    for(int kk=0;kk<32;kk++){
      float av[4],bv[4];
      #pragma unroll
      for(int x=0;x<4;x++) av[x]=As[ti*4+x][kk];
      #pragma unroll
      for(int y=0;y<4;y++) bv[y]=Bs[kk][vi*4+y];
      #pragma unroll
      for(int x=0;x<4;x++)
        #pragma unroll
        for(int y=0;y<4;y++) acc[x][y]+=av[x]*bv[y];
    }
    __syncthreads();
  }
  #pragma unroll
  for(int x=0;x<4;x++){
    int row=r0+ti*4+x;
    float b=ldf(b0,row,f);
    #pragma unroll
    for(int y=0;y<4;y++) embW[row*256+v0+vi*4+y]=acc[x][y]+b;
  }
}

// ---- layer-0 sliced prepack, TRANSPOSED rows (row-in-tile = dd*4+G) so one
// f32x4 acc holds all 4 gates of one dim (register-local nonlinearity).
__global__ void k_wpkA(const void* __restrict__ Wh0, const void* __restrict__ Wi0,
                       const int* __restrict__ flags, ushort_t* __restrict__ PA){
  int f=flags[0];
  int idx=blockIdx.x*256+threadIdx.x;
  if(idx>=1179648) return;
  int j=idx&7, l=(idx>>3)&63, rest=idx>>9;
  int c=rest%18, t2=rest/18, w=t2&7, r=t2>>3;
  int tr=l&15, q4=l>>4;
  int G=tr&3, dd=tr>>2;
  int row=G*512 + r*32 + w*4 + dd;
  int k=c*32 + q4*8 + j;
  float val = (k<512)? ldf(Wh0,row*512+k,f) : ldf(Wi0,row*576+k,f);
  H16 hx; hx.h=(f16)val; PA[idx]=hx.s;
}
// ---- layer-1 sliced prepack, transposed ----
__global__ void k_wpkB(const void* __restrict__ Wi1, const void* __restrict__ Wh1,
                       const int* __restrict__ flags, ushort_t* __restrict__ PB){
  int f=flags[0];
  int idx=blockIdx.x*256+threadIdx.x;
  if(idx>=2097152) return;
  int j=idx&7, l=(idx>>3)&63, rest=idx>>9;
  int c=rest&31, t2=rest>>5, w=t2&7, r=t2>>3;
  int tr=l&15, q4=l>>4;
  int G=tr&3, dd=tr>>2;
  int row=G*512 + r*32 + w*4 + dd;
  int k=c*32 + q4*8 + j;
  float val = (k<512)? ldf(Wi1,row*512+k,f) : ldf(Wh1,row*512+k-512,f);
  H16 hx; hx.h=(f16)val; PB[idx]=hx.s;
}

// W_if prepack into MFMA A-frags; zeroes FL; loads b_ifF.
__global__ void k_wifP(const void* __restrict__ W_if, const void* __restrict__ b_if,
                       const int* __restrict__ flags,
                       ushort_t* __restrict__ PW, float* __restrict__ b_ifF,
                       unsigned* __restrict__ FLz){
  int f=flags[0];
  int idx=blockIdx.x*256+threadIdx.x;
  if(idx<73728){
    int j=idx&7, l=(idx>>3)&63, c=(idx>>9)&15, tile=idx>>13;
    int row=tile*16+(l&15);
    int k=c*32+(l>>4)*8+j;
    float val=(row<135)? ldf(W_if,row*512+k,f) : 0.f;
    H16 hx; hx.h=(f16)val; PW[idx]=hx.s;
  }
  if(idx<64) FLz[idx]=0u;
  if(idx<135) b_ifF[idx]=ldf(b_if,idx,f);
}

// TILED k_wc: Wc[256,576] = W_fc[256,512] @ W_out[512,576]; bc = b_fc + W_fc@b_out.
__global__ void __launch_bounds__(256) k_wc(const void* __restrict__ W_fc, const void* __restrict__ W_out,
                     const void* __restrict__ b_out, const void* __restrict__ b_fc,
                     const int* __restrict__ flags,
                     float* __restrict__ Wc, float* __restrict__ bc){
  int f=flags[0];
  int v0=blockIdx.x*64, j0=blockIdx.y*64;
  __shared__ float As[64][33];
  __shared__ float Bs[32][65];
  __shared__ float red[64][4];
  int tid=threadIdx.x;
  int ti=tid>>4, vi=tid&15;
  float acc[4][4]={};
  for(int k0=0;k0<512;k0+=32){
    for(int i=tid;i<64*32;i+=256){
      int vv=i>>5,k=i&31;
      As[vv][k]=ldf(W_fc,(v0+vv)*512+k0+k,f);
    }
    for(int i=tid;i<64*32;i+=256){
      int jj=i>>5,k=i&31;
      Bs[k][jj]=ldf(W_out,(k0+k)*576+j0+jj,f);
    }
    __syncthreads();
    #pragma unroll 8
    for(int kk=0;kk<32;kk++){
      float av[4],bv[4];
      #pragma unroll
      for(int x=0;x<4;x++) av[x]=As[ti*4+x][kk];
      #pragma unroll
      for(int y=0;y<4;y++) bv[y]=Bs[kk][vi*4+y];
      #pragma unroll
      for(int x=0;x<4;x++)
        #pragma unroll
        for(int y=0;y<4;y++) acc[x][y]+=av[x]*bv[y];
    }
    __syncthreads();
  }
  #pragma unroll
  for(int x=0;x<4;x++){
    int v=v0+ti*4+x;
    #pragma unroll
    for(int y=0;y<4;y++) Wc[v*576+j0+vi*4+y]=acc[x][y];
  }
  if(blockIdx.y==0){
    int v=tid>>2, pp=tid&3;
    float a=0.f;
    for(int d=pp*128;d<pp*128+128;d++) a+=ldf(W_fc,(v0+v)*512+d,f)*ldf(b_out,d,f);
    red[v][pp]=a;
    __syncthreads();
    if(pp==0) bc[v0+v]=ldf(b_fc,v0+v,f)+red[v][0]+red[v][1]+red[v][2]+red[v][3];
  }
}

// ---------------- grouped recurrence (2-hop) + hop-covering prefetch ----------------
// 4 groups x 16 blocks; block (g,r) owns dims [32r,32r+32); L2-resident slices.
// vs round 10: all 5 MFMA sections use SPLIT (even/odd) accumulators to halve
// the 16-deep serial MFMA dependency chain. Everything else unchanged.
__global__ void __launch_bounds__(512, 2) k_dnc3(
    const int* __restrict__ tokens, const void* __restrict__ b1, const int* __restrict__ flags,
    const float* __restrict__ embW, const ushort_t* __restrict__ PA, const ushort_t* __restrict__ PB,
    const ushort_t* __restrict__ PW, const float* __restrict__ b_ifF,
    u64* GX0, u64* GX1, unsigned* FL,
    bf16* __restrict__ cat)
{
  const int bid = blockIdx.x;
  const int g   = bid>>4, r = bid&15;
  const int tid = threadIdx.x;
  const int wv  = tid>>6, l = tid&63;
  const int lm  = l&15,  q4 = l>>4;
  const int mb  = tid>>5, mu = tid&31;     // machinery mapping (batch, slot)
  const int f32i = flags[0];

  __shared__ __align__(16) u64 HB[4352];   // [0..2047] h0 | [2048..4095] h1 | [4096..4351] lr frags
  __shared__ f16  sh_pub[512];
  __shared__ int  tokL[16];
  __shared__ float b_ifL[144];
  __shared__ float xis2[16*149];
  __shared__ float s_pre[16*112];          // precomputed transcendentals per batch
  __shared__ float s_mem[1280], s_mem2[1280], s_link[400], s_link2[400];
  __shared__ float s_prec[80], s_prec2[80], s_rwp[320], s_rw[320];
  __shared__ float s_wwp[80], s_ww[80], s_usage[80], s_wl[80];
  __shared__ float s_rl[320], s_fwd[320], s_bwd[320], s_wsum[16];
  __shared__ float rvbuf[1024];

#define WAITG(TGT) do{ if(tid<16){ unsigned _tg=(unsigned)(TGT); int _wd=0; \
    while(ald32(&FL[g*16+tid]) < _tg && _wd<50000000){ __builtin_amdgcn_s_sleep(1); _wd++; } } \
  __syncthreads(); }while(0)
#define PUBF(VAL) do{ __syncthreads(); \
  if(tid==0) ast32(&FL[g*16+r],(unsigned)(VAL)); }while(0)
#define XI(i) xis2[mb*149+(i)]
#define WB() __builtin_amdgcn_wave_barrier()

  const f16x8* HBv=(const f16x8*)HB;
  const uint4* PAv=(const uint4*)PA;
  const uint4* PBv=(const uint4*)PB;
  const uint4* PWv=(const uint4*)PW;

  // per-thread biases for (dim1 = r*32+wv*4+q4), 4 gates
  const int dim1 = r*32 + wv*4 + q4;
  const float b1Li=ldf(b1,dim1,f32i), b1Lf=ldf(b1,512+dim1,f32i),
              b1Lg=ldf(b1,1024+dim1,f32i), b1Lo=ldf(b1,1536+dim1,f32i);

  if(tid<144) b_ifL[tid]=(tid<135)? b_ifF[tid] : 0.f;
  for(int i=tid;i<1280;i+=512) s_mem[i]=0.f;
  for(int i=tid;i<400;i+=512) s_link[i]=0.f;
  for(int i=tid;i<320;i+=512) s_rwp[i]=0.f;
  if(tid<80){ s_prec[tid]=0.f; s_wwp[tid]=0.f; s_usage[tid]=0.f; }
  float c0s=0.f, c1s=0.f;

  // ---- prologue t=0: h0(0)=f(em(0)); h1(0)=g(h0(0)) ----
  if(tid<16) tokL[tid]=tokens[(g*16+tid)*512];
  __syncthreads();
  {
    int tok=tokL[lm];
    float ei=embW[dim1*256+tok];
    float eg=embW[262144+dim1*256+tok];
    float eo=embW[393216+dim1*256+tok];
    c0s = sigf(ei)*tanhf(eg);
    sh_pub[(wv*4+q4)*16+lm]=(f16)(sigf(eo)*tanhf(c0s));
  }
  __syncthreads();
  if(tid<128){
    int ks=tid>>4, b2=tid&15;
    U64H4 pk;
    #pragma unroll
    for(int i=0;i<4;i++) pk.h[i]=sh_pub[(ks*4+i)*16+b2];
    ast64(&GX0[g*4096+((4*r+(ks>>1))*16+b2)*2+(ks&1)], pk.u);
  }
  PUBF(2u);            // alpha(0)
  WAITG(2u);
  {
    u64 s0=ald64(&GX0[g*4096+tid      ]);
    u64 s1=ald64(&GX0[g*4096+tid+512  ]);
    u64 s2=ald64(&GX0[g*4096+tid+1024 ]);
    u64 s3=ald64(&GX0[g*4096+tid+1536 ]);
    HB[tid]=s0; HB[tid+512]=s1; HB[tid+1024]=s2; HB[tid+1536]=s3;
  }
  __syncthreads();
  {
    f32x4 acc1=(f32x4){0.f,0.f,0.f,0.f};
    #pragma unroll
    for(int c=0;c<16;c++){
      U4H8 wf; wf.u=PBv[((r*8+wv)*32+c)*64+l];
      f16x8 bfr=HBv[(c*4+q4)*16+lm];
      acc1=__builtin_amdgcn_mfma_f32_16x16x32_f16(wf.h,bfr,acc1,0,0,0);
    }
    float gi=acc1[0]+b1Li, gg=acc1[2]+b1Lg, go=acc1[3]+b1Lo;
    c1s=sigf(gi)*tanhf(gg);
    sh_pub[(wv*4+q4)*16+lm]=(f16)(sigf(go)*tanhf(c1s));
  }
  __syncthreads();
  if(tid<128){
    int ks=tid>>4, b2=tid&15;
    U64H4 pk;
    #pragma unroll
    for(int i=0;i<4;i++) pk.h[i]=sh_pub[(ks*4+i)*16+b2];
    ast64(&GX1[g*4096+((4*r+(ks>>1))*16+b2)*2+(ks&1)], pk.u);
  }
  PUBF(3u);            // beta(0)

  // ---- main loop ----
  for(int tt=0;tt<512;tt++){
    const int p=tt&1, pn=p^1;

    // cover1: A p1 (16 chunks, split accumulators) on h0(tt) in HB[0..2047]
    f32x4 accA0=(f32x4){0.f,0.f,0.f,0.f};
    f32x4 accA1=(f32x4){0.f,0.f,0.f,0.f};
    #pragma unroll
    for(int c=0;c<16;c+=2){
      U4H8 wf0; wf0.u=PAv[((r*8+wv)*18+c)*64+l];
      f16x8 bf0=HBv[(c*4+q4)*16+lm];
      accA0=__builtin_amdgcn_mfma_f32_16x16x32_f16(wf0.h,bf0,accA0,0,0,0);
      U4H8 wf1; wf1.u=PAv[((r*8+wv)*18+c+1)*64+l];
      f16x8 bf1=HBv[((c+1)*4+q4)*16+lm];
      accA1=__builtin_amdgcn_mfma_f32_16x16x32_f16(wf1.h,bf1,accA1,0,0,0);
    }
    // prefetch em(tt+1), A2 lr-frag weights, and P3 W_if frags (hop-covered)
    float em0,em1,em2,em3;
    {
      int tn=(tt<511)?tt+1:511;
      int tok=tokens[(g*16+lm)*512+tn];
      em0=embW[dim1*256+tok]; em1=embW[131072+dim1*256+tok];
      em2=embW[262144+dim1*256+tok]; em3=embW[393216+dim1*256+tok];
    }
    uint4 pfA2[2];
    #pragma unroll
    for(int c2=0;c2<2;c2++) pfA2[c2]=PAv[((r*8+wv)*18+16+c2)*64+l];
    uint4 pfP3[16];
    #pragma unroll
    for(int cc=0;cc<16;cc++) pfP3[cc]=PWv[(wv*16+cc)*64+l];

    WAITG(2*tt+3);     // beta(tt)

    // stage h1(tt) -> HB[2048..4095]
    {
      u64 s0=ald64(&GX1[g*4096+p*2048+tid      ]);
      u64 s1=ald64(&GX1[g*4096+p*2048+tid+512  ]);
      u64 s2=ald64(&GX1[g*4096+p*2048+tid+1024 ]);
      u64 s3=ald64(&GX1[g*4096+p*2048+tid+1536 ]);
      HB[2048+tid]=s0; HB[2048+tid+512]=s1; HB[2048+tid+1024]=s2; HB[2048+tid+1536]=s3;
    }
    __syncthreads();

    // ====== P3(tt): xi = W_if @ h1 via MFMA (prefetched weights, split acc) ======
    {
      f32x4 xa0=(f32x4){0.f,0.f,0.f,0.f};
      f32x4 xa1=(f32x4){0.f,0.f,0.f,0.f};
      #pragma unroll
      for(int cc=0;cc<16;cc+=2){
        U4H8 t0; t0.u=pfP3[cc];
        f16x8 bf0=HBv[1024+(cc*4+q4)*16+lm];
        xa0=__builtin_amdgcn_mfma_f32_16x16x32_f16(t0.h,bf0,xa0,0,0,0);
        U4H8 t1; t1.u=pfP3[cc+1];
        f16x8 bf1=HBv[1024+((cc+1)*4+q4)*16+lm];
        xa1=__builtin_amdgcn_mfma_f32_16x16x32_f16(t1.h,bf1,xa1,0,0,0);
      }
      f32x4 xa=xa0+xa1;
      #pragma unroll
      for(int reg=0;reg<4;reg++){
        int row=wv*16+q4*4+reg;
        xis2[lm*149+row]=xa[reg]+b_ifL[row];
      }
      if(wv==0){
        f32x4 xb0=(f32x4){0.f,0.f,0.f,0.f};
        f32x4 xb1=(f32x4){0.f,0.f,0.f,0.f};
        #pragma unroll
        for(int cc=0;cc<16;cc+=2){
          U4H8 t0; t0.u=PWv[(128+cc)*64+l];
          f16x8 bf0=HBv[1024+(cc*4+q4)*16+lm];
          xb0=__builtin_amdgcn_mfma_f32_16x16x32_f16(t0.h,bf0,xb0,0,0,0);
          U4H8 t1; t1.u=PWv[(128+cc+1)*64+l];
          f16x8 bf1=HBv[1024+((cc+1)*4+q4)*16+lm];
          xb1=__builtin_amdgcn_mfma_f32_16x16x32_f16(t1.h,bf1,xb1,0,0,0);
        }
        f32x4 xb=xb0+xb1;
        #pragma unroll
        for(int reg=0;reg<4;reg++){
          int row=128+q4*4+reg;
          xis2[lm*149+row]=xb[reg]+b_ifL[row];
        }
      }
    }
    __syncthreads();

    // ====== machinery (wave-local per batch, half-wave = 32 lanes) ======
    if(mu<16){
      s_pre[mb*112+mu]    =tanhf(XI(68+mu));
      s_pre[mb*112+16+mu] =sigf (XI(85+mu));
      s_pre[mb*112+32+mu] =tanhf(XI(101+mu));
    }
    s_pre[mb*112+48+mu]   =tanhf(XI(mu));
    s_pre[mb*112+48+32+mu]=tanhf(XI(32+mu));
    WB();
    // M1
    if(mu<5){
      int m=mu;
      float u=s_usage[mb*5+m]+(1.f-s_usage[mb*5+m])*s_wwp[mb*5+m];
      float psi=1.f;
      #pragma unroll
      for(int rr=0;rr<4;rr++) psi *= 1.f - sigf(XI(117+rr))*s_rwp[mb*20+rr*5+m];
      u*=psi; s_usage[mb*5+m]=u;
      float nm=0.f,dt=0.f,nk=0.f;
      #pragma unroll
      for(int w=0;w<16;w++){
        float mv=s_mem[mb*80+m*16+w], kv=s_pre[mb*112+w];
        nm+=mv*mv; dt+=mv*kv; nk+=kv*kv;
      }
      float sim=dt/((sqrtf(nm)+1e-6f)*(sqrtf(nk)+1e-6f));
      s_wl[mb*5+m]=sim*splus(XI(84));
    }
    WB();
    // M2a
    if(mu<5){
      int m=mu;
      float mx=s_wl[mb*5];
      #pragma unroll
      for(int j=1;j<5;j++) mx=fmaxf(mx,s_wl[mb*5+j]);
      float e=expf(s_wl[mb*5+m]-mx);
      float u=1e-6f+(1.f-1e-6f)*s_usage[mb*5+m];
      s_rl [mb*20+m]=u;   // scratch (overwritten by M4)
      s_bwd[mb*20+m]=e;   // scratch (overwritten by M4)
    }
    WB();
    // M2b: stable-rank allocation
    if(mu<5){
      int m=mu;
      float u=s_rl[mb*20+m], e=s_bwd[mb*20+m];
      float s=0.f, prod=1.f;
      #pragma unroll
      for(int j=0;j<5;j++){
        s+=s_bwd[mb*20+j];
        float uj=s_rl[mb*20+j];
        if(uj<u || (uj==u && j<m)) prod*=uj;
      }
      float wcw=e/s;
      float alloc=(1.f-u)*prod;
      float ag=sigf(XI(121)), wgg=sigf(XI(122));
      s_ww[mb*5+m]=wgg*(ag*alloc+(1.f-ag)*wcw);
    }
    WB();
    if(mu==0){
      float ws=0.f;
      #pragma unroll
      for(int m=0;m<5;m++) ws+=s_ww[mb*5+m];
      s_wsum[mb]=ws;
    }
    WB();
    // M3
    for(int k=mu;k<80;k+=32){
      int m=k>>4,w=k&15;
      float er=s_pre[mb*112+16+w], wv2=s_pre[mb*112+32+w];
      float w_=s_ww[mb*5+m];
      s_mem2[mb*80+k]=s_mem[mb*80+k]*(1.f-w_*er)+w_*wv2;
    }
    if(mu<25){
      int i=mu/5, j=mu-5*i;
      s_link2[mb*25+mu]=(i==j)?0.f:((1.f-s_ww[mb*5+i]-s_ww[mb*5+j])*s_link[mb*25+mu]+s_ww[mb*5+i]*s_prec[mb*5+j]);
    } else if(mu<30){
      int j=mu-25;
      s_prec2[mb*5+j]=(1.f-s_wsum[mb])*s_prec[mb*5+j]+s_ww[mb*5+j];
    }
    WB();
    // M4
    if(mu<20){
      int rr=mu/5, m=mu-5*rr;
      float nm=0.f,dt=0.f,nk=0.f;
      #pragma unroll
      for(int w=0;w<16;w++){
        float mv=s_mem2[mb*80+m*16+w], kv=s_pre[mb*112+48+rr*16+w];
        nm+=mv*mv; dt+=mv*kv; nk+=kv*kv;
      }
      float sim=dt/((sqrtf(nm)+1e-6f)*(sqrtf(nk)+1e-6f));
      s_rl[mb*20+mu]=sim*splus(XI(64+rr));
      float af=0.f, ab=0.f;
      #pragma unroll
      for(int j=0;j<5;j++) af+=s_link2[mb*25+m*5+j]*s_rwp[mb*20+rr*5+j];
      #pragma unroll
      for(int i=0;i<5;i++) ab+=s_link2[mb*25+i*5+m]*s_rwp[mb*20+rr*5+i];
      s_fwd[mb*20+rr*5+m]=af;
      s_bwd[mb*20+rr*5+m]=ab;
    }
    WB();
    // M5
    if(mu<20){
      int rr=mu/5;
      float mx=-1e30f;
      #pragma unroll
      for(int m=0;m<5;m++) mx=fmaxf(mx,s_rl[mb*20+rr*5+m]);
      float s=0.f;
      #pragma unroll
      for(int m=0;m<5;m++) s+=expf(s_rl[mb*20+rr*5+m]-mx);
      float rcw=expf(s_rl[mb*20+mu]-mx)/s;
      float q0=XI(123+3*rr),q1=XI(124+3*rr),q2=XI(125+3*rr);
      float m3=fmaxf(q0,fmaxf(q1,q2));
      float e0=expf(q0-m3),e1=expf(q1-m3),e2=expf(q2-m3);
      float inv=1.f/(e0+e1+e2);
      s_rw[mb*20+mu]=(e0*s_bwd[mb*20+mu]+e1*s_fwd[mb*20+mu]+e2*rcw)*inv;
    }
    WB();
    // M6
    for(int k=mu;k<64;k+=32){
      int rr=k>>4,w=k&15;
      float a=0.f;
      #pragma unroll
      for(int m=0;m<5;m++) a+=s_rw[mb*20+rr*5+m]*s_mem2[mb*80+m*16+w];
      rvbuf[mb*64+k]=a;
    }
    for(int k=mu;k<80;k+=32) s_mem[mb*80+k]=s_mem2[mb*80+k];
    if(mu<25) s_link[mb*25+mu]=s_link2[mb*25+mu];
    else if(mu<30) s_prec[mb*5+mu-25]=s_prec2[mb*5+mu-25];
    if(mu<20) s_rwp[mb*20+mu]=s_rw[mb*20+mu];
    if(mu>=27&&mu<32){ int m=mu-27; s_wwp[mb*5+m]=s_ww[mb*5+m]; }
    __syncthreads();

    if(tt==511){
      int cb=((g*16+r)*512+tt)*576;
      if(tid<128){
        int kg=tid>>1, e=tid&1;
        U64H4 pv; pv.u=HB[2048+(kg*16+r)*2+e];
        #pragma unroll
        for(int i=0;i<4;i++){
          float x=(float)pv.h[i];
          cat[cb+kg*8+e*4+i]=__float2bfloat16(fminf(fmaxf(x,-20.f),20.f));
        }
      }
      if(tid<64) cat[cb+512+tid]=__float2bfloat16(rvbuf[r*64+tid]);
      break;
    }

    // build lr B-frags in HB[4096..4351]
    if(tid<256){
      int kg=tid>>5, rem=tid&31, b2=rem>>1, e=rem&1;
      U64H4 pk;
      #pragma unroll
      for(int i=0;i<4;i++) pk.h[i]=(f16)rvbuf[b2*64 + kg*8+e*4+i];
      HB[4096+(kg*16+b2)*2+e]=pk.u;
    }
    __syncthreads();
    // A p2: lr chunks (prefetched weights, one per split acc) + register-local nonlin0
    {
      U4H8 wf0; wf0.u=pfA2[0];
      f16x8 bf0=HBv[2048+(0*4+q4)*16+lm];
      accA0=__builtin_amdgcn_mfma_f32_16x16x32_f16(wf0.h,bf0,accA0,0,0,0);
      U4H8 wf1; wf1.u=pfA2[1];
      f16x8 bf1=HBv[2048+(1*4+q4)*16+lm];
      accA1=__builtin_amdgcn_mfma_f32_16x16x32_f16(wf1.h,bf1,accA1,0,0,0);
    }
    {
      f32x4 accA=accA0+accA1;
      float gi=accA[0]+em0, gf=accA[1]+em1, gg=accA[2]+em2, go=accA[3]+em3;
      float c0=sigf(gf)*c0s+sigf(gi)*tanhf(gg);
      c0s=c0;
      sh_pub[(wv*4+q4)*16+lm]=(f16)(sigf(go)*tanhf(c0));
    }
    __syncthreads();
    if(tid<128){
      int ks=tid>>4, b2=tid&15;
      U64H4 pk;
      #pragma unroll
      for(int i=0;i<4;i++) pk.h[i]=sh_pub[(ks*4+i)*16+b2];
      ast64(&GX0[g*4096+pn*2048+((4*r+(ks>>1))*16+b2)*2+(ks&1)], pk.u);
    }
    PUBF(2*tt+4);      // alpha(tt+1)

    // cover2: B p1 (Wh1 chunks, split acc) on h1(tt); cat stores;
    // prefetch B p2 frags (consumed after the alpha wait)
    f32x4 accB0=(f32x4){0.f,0.f,0.f,0.f};
    f32x4 accB1=(f32x4){0.f,0.f,0.f,0.f};
    #pragma unroll
    for(int c=16;c<32;c+=2){
      U4H8 wf0; wf0.u=PBv[((r*8+wv)*32+c)*64+l];
      f16x8 bf0=HBv[1024+((c-16)*4+q4)*16+lm];
      accB0=__builtin_amdgcn_mfma_f32_16x16x32_f16(wf0.h,bf0,accB0,0,0,0);
      U4H8 wf1; wf1.u=PBv[((r*8+wv)*32+c+1)*64+l];
      f16x8 bf1=HBv[1024+((c-15)*4+q4)*16+lm];
      accB1=__builtin_amdgcn_mfma_f32_16x16x32_f16(wf1.h,bf1,accB1,0,0,0);
    }
    uint4 pfB2[16];
    #pragma unroll
    for(int c=0;c<16;c++) pfB2[c]=PBv[((r*8+wv)*32+c)*64+l];
    {
      int cb=((g*16+r)*512+tt)*576;
      if(tid<128){
        int kg=tid>>1, e=tid&1;
        U64H4 pv; pv.u=HB[2048+(kg*16+r)*2+e];
        #pragma unroll
        for(int i=0;i<4;i++){
          float x=(float)pv.h[i];
          cat[cb+kg*8+e*4+i]=__float2bfloat16(fminf(fmaxf(x,-20.f),20.f));
        }
      }
      if(tid<64) cat[cb+512+tid]=__float2bfloat16(rvbuf[r*64+tid]);
    }

    WAITG(2*tt+4);     // alpha(tt+1)

    // B p2: stage h0(tt+1), Wi1 chunks (prefetched, split acc), nonlin1
    {
      u64 s0=ald64(&GX0[g*4096+pn*2048+tid      ]);
      u64 s1=ald64(&GX0[g*4096+pn*2048+tid+512  ]);
      u64 s2=ald64(&GX0[g*4096+pn*2048+tid+1024 ]);
      u64 s3=ald64(&GX0[g*4096+pn*2048+tid+1536 ]);
      HB[tid]=s0; HB[tid+512]=s1; HB[tid+1024]=s2; HB[tid+1536]=s3;
    }
    __syncthreads();
    #pragma unroll
    for(int c=0;c<16;c+=2){
      U4H8 wf0; wf0.u=pfB2[c];
      f16x8 bf0=HBv[(c*4+q4)*16+lm];
      accB0=__builtin_amdgcn_mfma_f32_16x16x32_f16(wf0.h,bf0,accB0,0,0,0);
      U4H8 wf1; wf1.u=pfB2[c+1];
      f16x8 bf1=HBv[((c+1)*4+q4)*16+lm];
      accB1=__builtin_amdgcn_mfma_f32_16x16x32_f16(wf1.h,bf1,accB1,0,0,0);
    }
    {
      f32x4 accB=accB0+accB1;
      float gi=accB[0]+b1Li, gf=accB[1]+b1Lf, gg=accB[2]+b1Lg, go=accB[3]+b1Lo;
      float c1=sigf(gf)*c1s+sigf(gi)*tanhf(gg);
      c1s=c1;
      sh_pub[(wv*4+q4)*16+lm]=(f16)(sigf(go)*tanhf(c1));
    }
    __syncthreads();
    if(tid<128){
      int ks=tid>>4, b2=tid&15;
      U64H4 pk;
      #pragma unroll
      for(int i=0;i<4;i++) pk.h[i]=sh_pub[(ks*4+i)*16+b2];
      ast64(&GX1[g*4096+pn*2048+((4*r+(ks>>1))*16+b2)*2+(ks&1)], pk.u);
    }
    PUBF(2*tt+5);      // beta(tt+1)
  }
#undef WAITG
#undef PUBF
#undef XI
#undef WB
}

// ---------------- final output GEMM (f32 out) ----------------
__global__ void __launch_bounds__(256) k_out(const bf16* __restrict__ cat,
                                             const float* __restrict__ Wc,
                                             const float* __restrict__ bc,
                                             float* __restrict__ outp){
  int t0=blockIdx.x*64, v0=blockIdx.y*64, b=blockIdx.z;
  __shared__ float As[64][33];
  __shared__ float Bs[32][65];
  int tid=threadIdx.x;
  int ti=tid>>4, vi=tid&15;
  float acc[4][4]={};
  for(int k0=0;k0<576;k0+=32){
    for(int i=tid;i<64*32;i+=256){
      int rr=i>>5,k=i&31;
      As[rr][k]=b2f(cat[(b*512+t0+rr)*576+k0+k]);
    }
    for(int i=tid;i<64*32;i+=256){
      int v=i>>5,k=i&31;
      Bs[k][v]=Wc[(v0+v)*576+k0+k];
    }
    __syncthreads();
    #pragma unroll 8
    for(int kk=0;kk<32;kk++){
      float av[4],bv[4];
      #pragma unroll
      for(int x=0;x<4;x++) av[x]=As[ti*4+x][kk];
      #pragma unroll
      for(int y=0;y<4;y++) bv[y]=Bs[kk][vi*4+y];
      #pragma unroll
      for(int x=0;x<4;x++)
        #pragma unroll
        for(int y=0;y<4;y++) acc[x][y]+=av[x]*bv[y];
    }
    __syncthreads();
  }
  #pragma unroll
  for(int y=0;y<4;y++){
    int v=v0+vi*4+y;
    float bcv=bc[v];
    #pragma unroll
    for(int x=0;x<4;x++){
      int tt=t0+ti*4+x;
      outp[(b*256+v)*512+tt]=acc[x][y]+bcv;
    }
  }
}

extern "C" void kernel_launch(void* const* d_in, const int* in_sizes, int n_in,
                              void* d_out, int out_size, void* d_ws, size_t ws_size,
                              hipStream_t stream) {
  const int*  tokens = (const int*) d_in[0];
  const void* emb    = d_in[1];
  const void* Wi0    = d_in[2];
  const void* Wh0    = d_in[3];
  const void* b0     = d_in[4];
  const void* Wi1    = d_in[5];
  const void* Wh1    = d_in[6];
  const void* b1     = d_in[7];
  const void* W_if   = d_in[8];
  const void* b_if   = d_in[9];
  const void* W_out  = d_in[10];
  const void* b_out  = d_in[11];
  const void* W_fc   = d_in[12];
  const void* b_fc   = d_in[13];

  static const int expect[14] = {64*512, 256*512, 2048*576, 2048*512, 2048,
                                 2048*512, 2048*512, 2048, 135*512, 135,
                                 512*576, 512, 256*512, 256};
  bool ok = (n_in == 14);
  if(ok) for(int i=0;i<14;i++) if(in_sizes[i]!=expect[i]) ok=false;

  int*      flags = (int*)d_ws;                   // [0]=dtype flag
  float*    embW  = (float*)d_ws + 64;            // 2048*256
  ushort_t* PA    = (ushort_t*)(embW + 524288);   // 1179648 f16 used (region 1310720; FL at +1179648)
  ushort_t* PB    = PA + 1310720;                 // 2097152 f16
  float*    Wreg  = (float*)(PB + 2097152);       // PW (73728 f16) lives here
  float*    b_ifF = Wreg + 69632;                 // 160
  float*    Wc    = b_ifF + 160;                  // 147456
  float*    bc    = Wc + 147456;                  // 256
  u64*      GX0   = (u64*)(bc + 256);             // 16384 u64 = [4 grp][2 ph][2048]
  u64*      GX1   = GX0 + 16384;                  // 16384 u64
  u64*      GXL   = GX1 + 16384;                  // 2048 u64 (unused, layout keep)
  bf16*     cat   = (bf16*)(GXL + 2048);          // 64*512*576
  unsigned* FL    = (unsigned*)(PA + 1179648);    // 64 dwords: 4 groups x 16 flags
  ushort_t* PW    = (ushort_t*)Wreg;              // 73728 f16

  size_t need = 9783168ull + 278528ull + 37748736ull;   // = 47,810,432 B
  if(!ok || ws_size < need){
    hipMemsetAsync(d_out, 0, (size_t)out_size*4, stream);
    return;
  }

  k_detect<<<dim3(1), dim3(256), 0, stream>>>(emb, flags);
  k_embW<<<dim3(32,4), dim3(256), 0, stream>>>(emb, Wi0, b0, flags, embW);
  k_wpkA<<<dim3(4608), dim3(256), 0, stream>>>(Wh0, Wi0, flags, PA);
  k_wpkB<<<dim3(8192), dim3(256), 0, stream>>>(Wi1, Wh1, flags, PB);
  k_wifP<<<dim3(288), dim3(256), 0, stream>>>(W_if, b_if, flags, PW, b_ifF, FL);
  k_wc  <<<dim3(4,9),  dim3(256), 0, stream>>>(W_fc, W_out, b_out, b_fc, flags, Wc, bc);

  void* kargs[] = {
    (void*)&tokens, (void*)&b1, (void*)&flags,
    (void*)&embW, (void*)&PA, (void*)&PB,
    (void*)&PW, (void*)&b_ifF,
    (void*)&GX0, (void*)&GX1, (void*)&FL,
    (void*)&cat
  };
  hipLaunchCooperativeKernel((const void*)k_dnc3, dim3(64), dim3(512), kargs, 0, stream);

  k_out<<<dim3(8,4,64), dim3(256), 0, stream>>>(cat, Wc, bc, (float*)d_out);
}